// Round 4
// baseline (286.697 us; speedup 1.0000x reference)
//
#include <hip/hip_runtime.h>

// MultiheadSelfAttention w/ RoPE, causal. B=2 S=2048 D=1024 NH=16 HD=64.
// cvt_all -> gemm_qkv (m97-style global_load_lds staging) -> rope
// -> attn (S^T/O^T, no-max softmax, BARRIER-FREE inner loop: K/V MFMA
//          fragments loaded DIRECTLY global->VGPR, L2-resident; P^T via
//          per-wave-private LDS only) -> gemm_out.
//
// R0-R3 lesson: VALU/MFMA busy-time is constant (~17/6.7us) across layouts,
// occupancy, barrier counts; all variance is stall time of the lockstep
// staging pipeline. K/V fragments are 16B-contiguous global row-segments
// (K[t][d0..], V^T[d][t0..]) == the staging load pattern, so LDS staging
// rearranges nothing. Drop it: no __syncthreads in the loop, waves free-run,
// K-frags software-pipelined one iteration ahead. K/V per head = 512KB,
// 4 heads/XCD -> L2-resident; qsub-pair redundancy absorbed by L1.

typedef unsigned short u16;
typedef unsigned int   u32;
typedef unsigned long long u64;
using s16x8 = __attribute__((ext_vector_type(8))) short;  // 8 bf16
using f32x4 = __attribute__((ext_vector_type(4))) float;  // 4 fp32 acc

__device__ __forceinline__ u16 f2bf(float f) {
  union { float f; u32 u; } v; v.f = f;
  return (u16)((v.u + 0x7fffu + ((v.u >> 16) & 1u)) >> 16);  // RNE
}
__device__ __forceinline__ float bf2f(u16 h) {
  union { u32 u; float f; } v; v.u = ((u32)h) << 16;
  return v.f;
}

// async 16B global->LDS (DMA; LDS dest = wave-uniform base + lane*16)
__device__ __forceinline__ void gl2lds(const u16* g, u16* l) {
  __builtin_amdgcn_global_load_lds(
      (const __attribute__((address_space(1))) void*)g,
      (__attribute__((address_space(3))) void*)l, 16, 0, 0);
}

// ---------------------------------------------------------------- cvt (fused)
__global__ __launch_bounds__(256) void cvt_all(
    const float* __restrict__ x,
    const float* __restrict__ wq, const float* __restrict__ wk,
    const float* __restrict__ wv, const float* __restrict__ wo,
    u16* __restrict__ xb, u16* __restrict__ wqb, u16* __restrict__ wkb,
    u16* __restrict__ wvb, u16* __restrict__ wob) {
  int e = (blockIdx.x * 256 + threadIdx.x) * 4;
  const float* src; u16* dst; int off;
  const int XN = 4 << 20;
  if (e < XN) { src = x; dst = xb; off = e; }
  else {
    int t = e - XN; int sel = t >> 20; off = t & ((1 << 20) - 1);
    src = sel == 0 ? wq : sel == 1 ? wk : sel == 2 ? wv : wo;
    dst = sel == 0 ? wqb : sel == 1 ? wkb : sel == 2 ? wvb : wob;
  }
  float4 v = *(const float4*)(src + off);
  ushort4 o;
  o.x = f2bf(v.x); o.y = f2bf(v.y); o.z = f2bf(v.z); o.w = f2bf(v.w);
  *(ushort4*)(dst + off) = o;
}

// ---------------------------------------------------------------- GEMM core
// m97 structure: C[128x128] = A[128xK] . W[128xK]^T, bf16, BK=32.
// LDS tiles [128][32] u16 UNPADDED (required by global_load_lds lane layout).
// Per K-tile: each wave issues 2 A-chunks + 2 B-chunks of 64 lanes x 16B.
__device__ __forceinline__ void gemm_core(
    const u16* __restrict__ A, const u16* __restrict__ W,
    u16* As, u16* Bs, int bm0, int bn0, f32x4 (&acc)[4][4]) {
  const int K = 1024;
  int tid = threadIdx.x;
  int wid = tid >> 6, lane = tid & 63, quad = lane >> 4, l15 = lane & 15;
  int wm = (wid >> 1) * 64, wn = (wid & 1) * 64;
  // chunk = row*4 + col8; LDS u16 offset = chunk*8 (row-major [128][32])
  int ch0 = wid * 128 + lane, ch1 = ch0 + 64;
  int r0 = ch0 >> 2, c0 = (ch0 & 3) * 8;
  int r1 = ch1 >> 2, c1 = (ch1 & 3) * 8;
  const u16* Ab = A + (size_t)bm0 * K;
  const u16* Wb = W + (size_t)bn0 * K;
  u16* lA0 = As + wid * 1024; u16* lA1 = lA0 + 512;  // wave-uniform bases
  u16* lB0 = Bs + wid * 1024; u16* lB1 = lB0 + 512;
  for (int k0 = 0; k0 < K; k0 += 32) {
    __syncthreads();  // prev tile's frag reads done
    gl2lds(Ab + (size_t)r0 * K + k0 + c0, lA0);
    gl2lds(Ab + (size_t)r1 * K + k0 + c1, lA1);
    gl2lds(Wb + (size_t)r0 * K + k0 + c0, lB0);
    gl2lds(Wb + (size_t)r1 * K + k0 + c1, lB1);
    __syncthreads();  // compiler drains vmcnt before barrier
    s16x8 af[4], bf[4];
#pragma unroll
    for (int mi = 0; mi < 4; mi++)
      af[mi] = *(const s16x8*)(As + (wm + mi * 16 + l15) * 32 + quad * 8);
#pragma unroll
    for (int ni = 0; ni < 4; ni++)
      bf[ni] = *(const s16x8*)(Bs + (wn + ni * 16 + l15) * 32 + quad * 8);
#pragma unroll
    for (int mi = 0; mi < 4; mi++)
#pragma unroll
      for (int ni = 0; ni < 4; ni++)
        acc[mi][ni] = __builtin_amdgcn_mfma_f32_16x16x32_bf16(
            af[mi], bf[ni], acc[mi][ni], 0, 0, 0);
  }
}

// ---------------------------------------------------------------- QKV proj
__global__ __launch_bounds__(256) void gemm_qkv(
    const u16* __restrict__ xb,
    const u16* __restrict__ wq, const u16* __restrict__ wk,
    const u16* __restrict__ wv,
    u16* __restrict__ qh, u16* __restrict__ kh, u16* __restrict__ vt) {
  __shared__ __align__(16) u16 As[128 * 32];
  __shared__ __align__(16) u16 Bs[128 * 32];
  int z = blockIdx.z;
  const u16* W = (z == 0) ? wq : (z == 1) ? wk : wv;
  int bm0 = blockIdx.y * 128, bn0 = blockIdx.x * 128;
  f32x4 acc[4][4];
  const f32x4 fz = {0.f, 0.f, 0.f, 0.f};
#pragma unroll
  for (int mi = 0; mi < 4; mi++)
#pragma unroll
    for (int ni = 0; ni < 4; ni++) acc[mi][ni] = fz;
  gemm_core(xb, W, As, Bs, bm0, bn0, acc);
  int tid = threadIdx.x, wid = tid >> 6, lane = tid & 63;
  int quad = lane >> 4, l15 = lane & 15;
  int wm = (wid >> 1) * 64, wn = (wid & 1) * 64;
  if (z < 2) {
    u16* dst = (z == 0) ? qh : kh;
#pragma unroll
    for (int mi = 0; mi < 4; mi++)
#pragma unroll
      for (int ni = 0; ni < 4; ni++)
#pragma unroll
        for (int r = 0; r < 4; r++) {
          int row = bm0 + wm + mi * 16 + quad * 4 + r;
          int col = bn0 + wn + ni * 16 + l15;
          int b = row >> 11, s = row & 2047, h = col >> 6, d = col & 63;
          dst[(((size_t)(b * 16 + h)) * 2048 + s) * 64 + d] =
              f2bf(acc[mi][ni][r]);
        }
  } else {
#pragma unroll
    for (int mi = 0; mi < 4; mi++)
#pragma unroll
      for (int ni = 0; ni < 4; ni++) {
        int row0 = bm0 + wm + mi * 16 + quad * 4;
        int col = bn0 + wn + ni * 16 + l15;
        int b = row0 >> 11, s0 = row0 & 2047, h = col >> 6, d = col & 63;
        u64 pk = (u64)f2bf(acc[mi][ni][0]) |
                 ((u64)f2bf(acc[mi][ni][1]) << 16) |
                 ((u64)f2bf(acc[mi][ni][2]) << 32) |
                 ((u64)f2bf(acc[mi][ni][3]) << 48);
        *(u64*)(vt + (((size_t)(b * 16 + h)) * 64 + d) * 2048 + s0) = pk;
      }
  }
}

// ---------------------------------------------------------------- out proj
__global__ __launch_bounds__(256) void gemm_out(
    const u16* __restrict__ ao, const u16* __restrict__ wo,
    float* __restrict__ out) {
  __shared__ __align__(16) u16 As[128 * 32];
  __shared__ __align__(16) u16 Bs[128 * 32];
  int bm0 = blockIdx.y * 128, bn0 = blockIdx.x * 128;
  f32x4 acc[4][4];
  const f32x4 fz = {0.f, 0.f, 0.f, 0.f};
#pragma unroll
  for (int mi = 0; mi < 4; mi++)
#pragma unroll
    for (int ni = 0; ni < 4; ni++) acc[mi][ni] = fz;
  gemm_core(ao, wo, As, Bs, bm0, bn0, acc);
  int tid = threadIdx.x, wid = tid >> 6, lane = tid & 63;
  int quad = lane >> 4, l15 = lane & 15;
  int wm = (wid >> 1) * 64, wn = (wid & 1) * 64;
#pragma unroll
  for (int mi = 0; mi < 4; mi++)
#pragma unroll
    for (int ni = 0; ni < 4; ni++)
#pragma unroll
      for (int r = 0; r < 4; r++) {
        int row = bm0 + wm + mi * 16 + quad * 4 + r;
        int col = bn0 + wn + ni * 16 + l15;
        out[(size_t)row * 1024 + col] = acc[mi][ni][r];
      }
}

// ---------------------------------------------------------------- RoPE
__global__ __launch_bounds__(256) void rope_k(
    u16* __restrict__ qh, u16* __restrict__ kh, const int* __restrict__ pos) {
  int i = blockIdx.x * 256 + threadIdx.x;
  int pair = i & 31;
  int s = (i >> 5) & 2047;
  int hb = i >> 16;
  float p = (float)pos[s];
  float freq = __expf(-0.28782313662425572f * (float)pair);
  float ang = p * freq, sn, cs;
  sincosf(ang, &sn, &cs);
  size_t base = ((size_t)hb * 2048 + s) * 64 + 2 * pair;
  {
    u32 u = *(const u32*)(qh + base);
    float x1 = bf2f((u16)(u & 0xffff)), x2 = bf2f((u16)(u >> 16));
    float r1 = (x1 * cs - x2 * sn) * 0.125f;
    float r2 = (x1 * sn + x2 * cs) * 0.125f;
    *(u32*)(qh + base) = (u32)f2bf(r1) | ((u32)f2bf(r2) << 16);
  }
  {
    u32 u = *(const u32*)(kh + base);
    float x1 = bf2f((u16)(u & 0xffff)), x2 = bf2f((u16)(u >> 16));
    float r1 = x1 * cs - x2 * sn;
    float r2 = x1 * sn + x2 * cs;
    *(u32*)(kh + base) = (u32)f2bf(r1) | ((u32)f2bf(r2) << 16);
  }
}

// ---------------------------------------------------------------- attention
// S^T = K.Q^T, O^T = V^T.P^T, no-max softmax (|score| bounded).
// Block: 32 q (2 waves qsub) x 64-t tiles split across 2 thalf wave-pairs.
// Grid 1024 = 4 blocks/CU, 2-phase pairing (qt = pi, then 63-pi) -> uniform
// ~33 iters/block, no tail. NO __syncthreads in the loop: K/V fragments are
// loaded directly global->VGPR (per-lane 16B row-segments; L2-resident),
// P^T goes through per-wave-private LDS (same-wave DS ordering). K-frags
// are software-pipelined one iteration ahead (issued right after last use,
// latency hidden under softmax+PV). Epilogue: 2 barriers/phase for the
// cross-thalf reduction (uniform across waves -> barriers match).

__global__ __launch_bounds__(256, 4) void attn_k(
    const u16* __restrict__ qh, const u16* __restrict__ kh,
    const u16* __restrict__ vt, u16* __restrict__ ao) {
  __shared__ __align__(16) u16 pt[4 * 512];       // per-wave P^T (4KB)
  __shared__ __align__(16) float redo[128 * 16];  // epilogue partial O (8KB)
  __shared__ __align__(16) float redl[128];       // epilogue partial lsum
  __shared__ __align__(16) u16 ow2[2 * 16 * 72];  // O staging, 144B rows
  int bid = blockIdx.x;
  int bh = bid & 31, pi = bid >> 5;
  int b = bh >> 4, h = bh & 15;
  int tid = threadIdx.x, wid = tid >> 6, lane = tid & 63;
  int quad = lane >> 4, l15 = lane & 15;
  int qsub = wid & 1, thalf = wid >> 1;
  const u16* qbase = qh + (size_t)bh * 2048 * 64;
  const u16* kbase = kh + (size_t)bh * 2048 * 64;
  const u16* vbase = vt + (size_t)bh * 64 * 2048;
  u16* ptw = pt + wid * 512;
  const f32x4 fz = {0.f, 0.f, 0.f, 0.f};
  int tb = thalf * 32;

#pragma unroll
  for (int phase = 0; phase < 2; phase++) {
    int qt = phase ? (63 - pi) : pi;
    int q0 = qt * 32, q0w = q0 + qsub * 16;
    s16x8 qf0 = *(const s16x8*)(qbase + (size_t)(q0w + l15) * 64 + quad * 8);
    s16x8 qf1 = *(const s16x8*)(qbase + (size_t)(q0w + l15) * 64 + 32 + quad * 8);
    f32x4 acc[4];
#pragma unroll
    for (int md = 0; md < 4; md++) acc[md] = fz;
    float lsum = 0.f;
    int qg = q0w + l15;
    int nt = (qt >> 1) + 1;
    // prologue: K fragments for it=0 (rows tb+mt*16+l15, cols quad*8 / +32)
    const u16* kp = kbase + (size_t)(tb + l15) * 64 + quad * 8;
    s16x8 ka00 = *(const s16x8*)(kp);
    s16x8 ka01 = *(const s16x8*)(kp + 32);
    s16x8 ka10 = *(const s16x8*)(kp + 1024);
    s16x8 ka11 = *(const s16x8*)(kp + 1024 + 32);
    for (int it = 0; it < nt; it++) {
      int t0 = it << 6;
      // V^T fragments for this iteration: rows md*16+l15, cols t0+tb+quad*8
      const u16* vp = vbase + (size_t)l15 * 2048 + t0 + tb + quad * 8;
      s16x8 va0 = *(const s16x8*)(vp);
      s16x8 va1 = *(const s16x8*)(vp + 16 * 2048);
      s16x8 va2 = *(const s16x8*)(vp + 32 * 2048);
      s16x8 va3 = *(const s16x8*)(vp + 48 * 2048);
      // QK^T for both mt using current K-frags
      f32x4 st0 = __builtin_amdgcn_mfma_f32_16x16x32_bf16(ka00, qf0, fz, 0, 0, 0);
      st0 = __builtin_amdgcn_mfma_f32_16x16x32_bf16(ka01, qf1, st0, 0, 0, 0);
      f32x4 st1 = __builtin_amdgcn_mfma_f32_16x16x32_bf16(ka10, qf0, fz, 0, 0, 0);
      st1 = __builtin_amdgcn_mfma_f32_16x16x32_bf16(ka11, qf1, st1, 0, 0, 0);
      // software-pipeline: next iteration's K-frags issued NOW (K regs dead);
      // latency hidden under softmax+PV. Clamped t1 keeps it branch-free.
      int t1 = (it + 1 < nt) ? ((it + 1) << 6) : 0;
      const u16* kp1 = kbase + (size_t)(t1 + tb + l15) * 64 + quad * 8;
      ka00 = *(const s16x8*)(kp1);
      ka01 = *(const s16x8*)(kp1 + 32);
      ka10 = *(const s16x8*)(kp1 + 1024);
      ka11 = *(const s16x8*)(kp1 + 1024 + 32);
      bool diag = (it == nt - 1);
      u64 pk0 = 0, pk1 = 0;
#pragma unroll
      for (int r = 0; r < 4; r++) {
        float p = __expf(st0[r]);
        if (diag) {
          int tg = t0 + tb + quad * 4 + r;
          if (tg > qg) p = 0.f;
        }
        lsum += p;
        pk0 |= ((u64)f2bf(p)) << (16 * r);
      }
#pragma unroll
      for (int r = 0; r < 4; r++) {
        float p = __expf(st1[r]);
        if (diag) {
          int tg = t0 + tb + 16 + quad * 4 + r;
          if (tg > qg) p = 0.f;
        }
        lsum += p;
        pk1 |= ((u64)f2bf(p)) << (16 * r);
      }
      // P^T frag layout: u16 addr = ((k>>3)*16 + q)*8 + (k&7);
      // k0 = mt*16+quad*4, q = l15. Per-wave private -> no barrier needed
      // (same-wave DS ops complete in order).
      *(u64*)(ptw + ((quad >> 1) * 16 + l15) * 8 + (quad & 1) * 4) = pk0;
      *(u64*)(ptw + (32 + (quad >> 1) * 16 + l15) * 8 + (quad & 1) * 4) = pk1;
      s16x8 pb = *(const s16x8*)(ptw + lane * 8);
      acc[0] = __builtin_amdgcn_mfma_f32_16x16x32_bf16(va0, pb, acc[0], 0, 0, 0);
      acc[1] = __builtin_amdgcn_mfma_f32_16x16x32_bf16(va1, pb, acc[1], 0, 0, 0);
      acc[2] = __builtin_amdgcn_mfma_f32_16x16x32_bf16(va2, pb, acc[2], 0, 0, 0);
      acc[3] = __builtin_amdgcn_mfma_f32_16x16x32_bf16(va3, pb, acc[3], 0, 0, 0);
    }
    lsum += __shfl_xor(lsum, 16, 64);
    lsum += __shfl_xor(lsum, 32, 64);
    __syncthreads();  // B1: epilogue entry (uniform; gates scratch reuse)
    if (thalf == 1) {
#pragma unroll
      for (int md = 0; md < 4; md++)
#pragma unroll
        for (int r = 0; r < 4; r++)
          redo[(qsub * 64 + lane) * 16 + md * 4 + r] = acc[md][r];
      redl[qsub * 64 + lane] = lsum;
    }
    __syncthreads();  // B2
    if (thalf == 0) {
#pragma unroll
      for (int md = 0; md < 4; md++)
#pragma unroll
        for (int r = 0; r < 4; r++)
          acc[md][r] += redo[(qsub * 64 + lane) * 16 + md * 4 + r];
      lsum += redl[qsub * 64 + lane];
      float rl = 1.0f / lsum;
      u16* ow = ow2 + qsub * 16 * 72;  // [16 q][72] u16, 16B-aligned rows
#pragma unroll
      for (int md = 0; md < 4; md++) {
        u64 ok = 0;
#pragma unroll
        for (int r = 0; r < 4; r++)
          ok |= ((u64)f2bf(acc[md][r] * rl)) << (16 * r);
        *(u64*)(ow + l15 * 72 + md * 16 + quad * 4) = ok;
      }
      int qq = lane >> 2, dc = lane & 3;
      uint4 o0 = *(uint4*)(ow + qq * 72 + dc * 16);
      uint4 o1 = *(uint4*)(ow + qq * 72 + dc * 16 + 8);
      size_t orow = (size_t)b * 2048 + q0 + qsub * 16 + qq;
      *(uint4*)(ao + orow * 1024 + h * 64 + dc * 16) = o0;
      *(uint4*)(ao + orow * 1024 + h * 64 + dc * 16 + 8) = o1;
    }
  }
}

// ---------------------------------------------------------------- launch
extern "C" void kernel_launch(void* const* d_in, const int* in_sizes, int n_in,
                              void* d_out, int out_size, void* d_ws,
                              size_t ws_size, hipStream_t stream) {
  const float* x  = (const float*)d_in[0];
  const int* pos  = (const int*)d_in[1];
  const float* Wq = (const float*)d_in[2];
  const float* Wk = (const float*)d_in[3];
  const float* Wv = (const float*)d_in[4];
  const float* Wo = (const float*)d_in[5];
  float* out = (float*)d_out;

  char* ws = (char*)d_ws;
  const size_t MB = 1u << 20;
  u16* xb  = (u16*)(ws);             // 8 MB  [4096][1024] bf16
  u16* wqb = (u16*)(ws + 8 * MB);
  u16* wkb = (u16*)(ws + 10 * MB);
  u16* wvb = (u16*)(ws + 12 * MB);
  u16* wob = (u16*)(ws + 14 * MB);
  u16* qhb = (u16*)(ws + 16 * MB);   // [B][NH][S][HD]
  u16* khb = (u16*)(ws + 24 * MB);
  u16* vtb = (u16*)(ws + 32 * MB);   // [B][NH][HD][S]
  u16* ao  = xb;  // xb dead after gemm_qkv

  cvt_all<<<8192, 256, 0, stream>>>(x, Wq, Wk, Wv, Wo,
                                    xb, wqb, wkb, wvb, wob);
  gemm_qkv<<<dim3(8, 32, 3), 256, 0, stream>>>(xb, wqb, wkb, wvb,
                                               qhb, khb, vtb);
  rope_k<<<8192, 256, 0, stream>>>(qhb, khb, pos);
  attn_k<<<1024, 256, 0, stream>>>(qhb, khb, vtb, ao);
  gemm_out<<<dim3(8, 32), 256, 0, stream>>>(ao, wob, out);
}

// Round 5
// 210.590 us; speedup vs baseline: 1.3614x; 1.3614x over previous
//
#include <hip/hip_runtime.h>

// MultiheadSelfAttention w/ RoPE, causal. B=2 S=2048 D=1024 NH=16 HD=64.
// cvt_all -> gemm_qkv (m97-style staging, RoPE FUSED into epilogue via
// per-block LDS sincos table + shfl_xor pair exchange) -> attn (R0-proven:
// S^T/O^T, no-max softmax, reg-prefetch lockstep pipeline) -> gemm_out.
//
// R1-R4 lessons: forced occupancy spills (R1); per-tile grids tail-imbalance
// (R2); dbuf/1-barrier no better than R0's 2-barrier (R3); direct
// global->VGPR frags serialize on L2 latency (R4). R0's attn structure is
// the measured best (52.9us) -> reverted verbatim. This round only removes
// the rope_k launch + its 32MB round-trip by fusing RoPE into gemm_qkv.

typedef unsigned short u16;
typedef unsigned int   u32;
typedef unsigned long long u64;
using s16x8 = __attribute__((ext_vector_type(8))) short;  // 8 bf16
using f32x4 = __attribute__((ext_vector_type(4))) float;  // 4 fp32 acc

__device__ __forceinline__ u16 f2bf(float f) {
  union { float f; u32 u; } v; v.f = f;
  return (u16)((v.u + 0x7fffu + ((v.u >> 16) & 1u)) >> 16);  // RNE
}
__device__ __forceinline__ float bf2f(u16 h) {
  union { u32 u; float f; } v; v.u = ((u32)h) << 16;
  return v.f;
}

// async 16B global->LDS (DMA; LDS dest = wave-uniform base + lane*16)
__device__ __forceinline__ void gl2lds(const u16* g, u16* l) {
  __builtin_amdgcn_global_load_lds(
      (const __attribute__((address_space(1))) void*)g,
      (__attribute__((address_space(3))) void*)l, 16, 0, 0);
}

// ---------------------------------------------------------------- cvt (fused)
__global__ __launch_bounds__(256) void cvt_all(
    const float* __restrict__ x,
    const float* __restrict__ wq, const float* __restrict__ wk,
    const float* __restrict__ wv, const float* __restrict__ wo,
    u16* __restrict__ xb, u16* __restrict__ wqb, u16* __restrict__ wkb,
    u16* __restrict__ wvb, u16* __restrict__ wob) {
  int e = (blockIdx.x * 256 + threadIdx.x) * 4;
  const float* src; u16* dst; int off;
  const int XN = 4 << 20;
  if (e < XN) { src = x; dst = xb; off = e; }
  else {
    int t = e - XN; int sel = t >> 20; off = t & ((1 << 20) - 1);
    src = sel == 0 ? wq : sel == 1 ? wk : sel == 2 ? wv : wo;
    dst = sel == 0 ? wqb : sel == 1 ? wkb : sel == 2 ? wvb : wob;
  }
  float4 v = *(const float4*)(src + off);
  ushort4 o;
  o.x = f2bf(v.x); o.y = f2bf(v.y); o.z = f2bf(v.z); o.w = f2bf(v.w);
  *(ushort4*)(dst + off) = o;
}

// ---------------------------------------------------------------- GEMM core
// m97 structure: C[128x128] = A[128xK] . W[128xK]^T, bf16, BK=32.
// LDS tiles [128][32] u16 UNPADDED (required by global_load_lds lane layout).
// Per K-tile: each wave issues 2 A-chunks + 2 B-chunks of 64 lanes x 16B.
__device__ __forceinline__ void gemm_core(
    const u16* __restrict__ A, const u16* __restrict__ W,
    u16* As, u16* Bs, int bm0, int bn0, f32x4 (&acc)[4][4]) {
  const int K = 1024;
  int tid = threadIdx.x;
  int wid = tid >> 6, lane = tid & 63, quad = lane >> 4, l15 = lane & 15;
  int wm = (wid >> 1) * 64, wn = (wid & 1) * 64;
  // chunk = row*4 + col8; LDS u16 offset = chunk*8 (row-major [128][32])
  int ch0 = wid * 128 + lane, ch1 = ch0 + 64;
  int r0 = ch0 >> 2, c0 = (ch0 & 3) * 8;
  int r1 = ch1 >> 2, c1 = (ch1 & 3) * 8;
  const u16* Ab = A + (size_t)bm0 * K;
  const u16* Wb = W + (size_t)bn0 * K;
  u16* lA0 = As + wid * 1024; u16* lA1 = lA0 + 512;  // wave-uniform bases
  u16* lB0 = Bs + wid * 1024; u16* lB1 = lB0 + 512;
  for (int k0 = 0; k0 < K; k0 += 32) {
    __syncthreads();  // prev tile's frag reads done
    gl2lds(Ab + (size_t)r0 * K + k0 + c0, lA0);
    gl2lds(Ab + (size_t)r1 * K + k0 + c1, lA1);
    gl2lds(Wb + (size_t)r0 * K + k0 + c0, lB0);
    gl2lds(Wb + (size_t)r1 * K + k0 + c1, lB1);
    __syncthreads();  // compiler drains vmcnt before barrier
    s16x8 af[4], bf[4];
#pragma unroll
    for (int mi = 0; mi < 4; mi++)
      af[mi] = *(const s16x8*)(As + (wm + mi * 16 + l15) * 32 + quad * 8);
#pragma unroll
    for (int ni = 0; ni < 4; ni++)
      bf[ni] = *(const s16x8*)(Bs + (wn + ni * 16 + l15) * 32 + quad * 8);
#pragma unroll
    for (int mi = 0; mi < 4; mi++)
#pragma unroll
      for (int ni = 0; ni < 4; ni++)
        acc[mi][ni] = __builtin_amdgcn_mfma_f32_16x16x32_bf16(
            af[mi], bf[ni], acc[mi][ni], 0, 0, 0);
  }
}

// ---------------------------------------------------------------- QKV proj
// RoPE fused for z<2: per-block LDS table of (cos,sin) for 128 rows x 32
// pairs (16 sincosf/thread, once), pair partner via __shfl_xor(v,1) (lane
// l15^1 holds col^1: wn, ni*16 even; l15 in [0,16)). Q also scaled 1/8.
__global__ __launch_bounds__(256) void gemm_qkv(
    const u16* __restrict__ xb,
    const u16* __restrict__ wq, const u16* __restrict__ wk,
    const u16* __restrict__ wv, const int* __restrict__ pos,
    u16* __restrict__ qh, u16* __restrict__ kh, u16* __restrict__ vt) {
  __shared__ __align__(16) u16 As[128 * 32];
  __shared__ __align__(16) u16 Bs[128 * 32];
  __shared__ __align__(16) float tab[128 * 32 * 2];  // (cs,sn) 32KB
  int z = blockIdx.z;
  const u16* W = (z == 0) ? wq : (z == 1) ? wk : wv;
  int bm0 = blockIdx.y * 128, bn0 = blockIdx.x * 128;
  int tid = threadIdx.x;
  if (z < 2) {
    for (int idx = tid; idx < 4096; idx += 256) {
      int rl = idx >> 5, pair = idx & 31;
      int s = (bm0 + rl) & 2047;
      float p = (float)pos[s];
      float freq = __expf(-0.28782313662425572f * (float)pair);
      float sn, cs;
      sincosf(p * freq, &sn, &cs);
      tab[idx * 2] = cs;
      tab[idx * 2 + 1] = sn;
    }
  }
  // no barrier needed here: gemm_core's first __syncthreads orders tab
  // writes before any epilogue read.
  f32x4 acc[4][4];
  const f32x4 fz = {0.f, 0.f, 0.f, 0.f};
#pragma unroll
  for (int mi = 0; mi < 4; mi++)
#pragma unroll
    for (int ni = 0; ni < 4; ni++) acc[mi][ni] = fz;
  gemm_core(xb, W, As, Bs, bm0, bn0, acc);
  int wid = tid >> 6, lane = tid & 63;
  int quad = lane >> 4, l15 = lane & 15;
  int wm = (wid >> 1) * 64, wn = (wid & 1) * 64;
  if (z < 2) {
    u16* dst = (z == 0) ? qh : kh;
    float qs = (z == 0) ? 0.125f : 1.0f;
#pragma unroll
    for (int mi = 0; mi < 4; mi++)
#pragma unroll
      for (int ni = 0; ni < 4; ni++) {
        int col = bn0 + wn + ni * 16 + l15;
        int h = col >> 6, d = col & 63;
        int pairi = d >> 1;
        int odd = d & 1;
#pragma unroll
        for (int r = 0; r < 4; r++) {
          int rl = wm + mi * 16 + quad * 4 + r;   // local row 0..127
          int row = bm0 + rl;
          int b = row >> 11, s = row & 2047;
          float v0 = acc[mi][ni][r];
          float vp = __shfl_xor(v0, 1, 64);       // pair partner (col^1)
          float cs = tab[(rl * 32 + pairi) * 2];
          float sn = tab[(rl * 32 + pairi) * 2 + 1];
          // even d: out = x1*cs - x2*sn ; odd d: out = x1*sn + x2*cs
          float o = odd ? (vp * sn + v0 * cs) : (v0 * cs - vp * sn);
          dst[(((size_t)(b * 16 + h)) * 2048 + s) * 64 + d] = f2bf(o * qs);
        }
      }
  } else {
#pragma unroll
    for (int mi = 0; mi < 4; mi++)
#pragma unroll
      for (int ni = 0; ni < 4; ni++) {
        int row0 = bm0 + wm + mi * 16 + quad * 4;
        int col = bn0 + wn + ni * 16 + l15;
        int b = row0 >> 11, s0 = row0 & 2047, h = col >> 6, d = col & 63;
        u64 pk = (u64)f2bf(acc[mi][ni][0]) |
                 ((u64)f2bf(acc[mi][ni][1]) << 16) |
                 ((u64)f2bf(acc[mi][ni][2]) << 32) |
                 ((u64)f2bf(acc[mi][ni][3]) << 48);
        *(u64*)(vt + (((size_t)(b * 16 + h)) * 64 + d) * 2048 + s0) = pk;
      }
  }
}

// ---------------------------------------------------------------- out proj
__global__ __launch_bounds__(256) void gemm_out(
    const u16* __restrict__ ao, const u16* __restrict__ wo,
    float* __restrict__ out) {
  __shared__ __align__(16) u16 As[128 * 32];
  __shared__ __align__(16) u16 Bs[128 * 32];
  int bm0 = blockIdx.y * 128, bn0 = blockIdx.x * 128;
  f32x4 acc[4][4];
  const f32x4 fz = {0.f, 0.f, 0.f, 0.f};
#pragma unroll
  for (int mi = 0; mi < 4; mi++)
#pragma unroll
    for (int ni = 0; ni < 4; ni++) acc[mi][ni] = fz;
  gemm_core(ao, wo, As, Bs, bm0, bn0, acc);
  int tid = threadIdx.x, wid = tid >> 6, lane = tid & 63;
  int quad = lane >> 4, l15 = lane & 15;
  int wm = (wid >> 1) * 64, wn = (wid & 1) * 64;
#pragma unroll
  for (int mi = 0; mi < 4; mi++)
#pragma unroll
    for (int ni = 0; ni < 4; ni++)
#pragma unroll
      for (int r = 0; r < 4; r++) {
        int row = bm0 + wm + mi * 16 + quad * 4 + r;
        int col = bn0 + wn + ni * 16 + l15;
        out[(size_t)row * 1024 + col] = acc[mi][ni][r];
      }
}

// ---------------------------------------------------------------- attention
// R0-proven version (52.9us): S^T = K.Q^T, O^T = V^T.P^T, no-max softmax.
// Block: 32 q (2 waves qsub) x 64-t tiles split across 2 thalf wave-pairs.
// Grid 1024 = 4 blocks/CU; linear id = bh + 32*pi -> same (b,h) same XCD.
// Register-prefetch pipeline hides K/V staging latency (single LDS buffer).
#define KTS 72
#define VTS 72
#define PTS 40
#define OTS 72

__global__ __launch_bounds__(256, 4) void attn_k(
    const u16* __restrict__ qh, const u16* __restrict__ kh,
    const u16* __restrict__ vt, u16* __restrict__ ao) {
  __shared__ __align__(16) u16 ks[64 * KTS];      // K-tile [t=64][d=64]
  __shared__ __align__(16) u16 vs[64 * VTS];      // V-tile [d=64][t=64]
  __shared__ __align__(16) u16 pt[4 * 16 * PTS];  // per-wave P^T (+ O scratch)
  int bid = blockIdx.x;
  int bh = bid & 31, pi = bid >> 5;
  int b = bh >> 4, h = bh & 15;
  int tid = threadIdx.x, wid = tid >> 6, lane = tid & 63;
  int quad = lane >> 4, l15 = lane & 15;
  int qsub = wid & 1, thalf = wid >> 1;
  const u16* qbase = qh + (size_t)bh * 2048 * 64;
  const u16* kbase = kh + (size_t)bh * 2048 * 64;
  const u16* vbase = vt + (size_t)bh * 64 * 2048;
  u16* ptw = pt + wid * 16 * PTS;
  const f32x4 fz = {0.f, 0.f, 0.f, 0.f};
  int srow = tid >> 2, sc = (tid & 3) * 8;

#pragma unroll
  for (int phase = 0; phase < 2; phase++) {
    int qt = phase ? (63 - pi) : pi;       // q-tile of 32
    int q0 = qt * 32, q0w = q0 + qsub * 16;
    s16x8 qf0 = *(const s16x8*)(qbase + (size_t)(q0w + l15) * 64 + quad * 8);
    s16x8 qf1 = *(const s16x8*)(qbase + (size_t)(q0w + l15) * 64 + 32 + quad * 8);
    f32x4 acc[4];
#pragma unroll
    for (int md = 0; md < 4; md++) acc[md] = fz;
    float lsum = 0.f;
    int qg = q0w + l15;
    int nt = (qt >> 1) + 1;
    uint4 rk0 = *(const uint4*)(kbase + (size_t)srow * 64 + sc);
    uint4 rk1 = *(const uint4*)(kbase + (size_t)srow * 64 + sc + 32);
    uint4 rv0 = *(const uint4*)(vbase + (size_t)srow * 2048 + sc);
    uint4 rv1 = *(const uint4*)(vbase + (size_t)srow * 2048 + sc + 32);
    for (int it = 0; it < nt; it++) {
      __syncthreads();
      *(uint4*)(ks + srow * KTS + sc) = rk0;
      *(uint4*)(ks + srow * KTS + sc + 32) = rk1;
      *(uint4*)(vs + srow * VTS + sc) = rv0;
      *(uint4*)(vs + srow * VTS + sc + 32) = rv1;
      if (it + 1 < nt) {
        int t1 = (it + 1) << 6;
        rk0 = *(const uint4*)(kbase + (size_t)(t1 + srow) * 64 + sc);
        rk1 = *(const uint4*)(kbase + (size_t)(t1 + srow) * 64 + sc + 32);
        rv0 = *(const uint4*)(vbase + (size_t)srow * 2048 + t1 + sc);
        rv1 = *(const uint4*)(vbase + (size_t)srow * 2048 + t1 + sc + 32);
      }
      __syncthreads();
      int t0 = it << 6, tb = thalf * 32;
      bool diag = (it == nt - 1);
#pragma unroll
      for (int mt = 0; mt < 2; mt++) {
        int krow = tb + mt * 16 + l15;
        s16x8 ka0 = *(const s16x8*)(ks + krow * KTS + quad * 8);
        s16x8 ka1 = *(const s16x8*)(ks + krow * KTS + 32 + quad * 8);
        f32x4 st = __builtin_amdgcn_mfma_f32_16x16x32_bf16(ka0, qf0, fz, 0, 0, 0);
        st = __builtin_amdgcn_mfma_f32_16x16x32_bf16(ka1, qf1, st, 0, 0, 0);
        u64 pk = 0;
#pragma unroll
        for (int r = 0; r < 4; r++) {
          float p = __expf(st[r]);
          if (diag) {
            int tg = t0 + tb + mt * 16 + quad * 4 + r;
            if (tg > qg) p = 0.f;
          }
          lsum += p;
          pk |= ((u64)f2bf(p)) << (16 * r);
        }
        *(u64*)(ptw + l15 * PTS + mt * 16 + quad * 4) = pk;
      }
      s16x8 pb = *(const s16x8*)(ptw + l15 * PTS + quad * 8);
#pragma unroll
      for (int md = 0; md < 4; md++) {
        s16x8 va = *(const s16x8*)(vs + (md * 16 + l15) * VTS + tb + quad * 8);
        acc[md] = __builtin_amdgcn_mfma_f32_16x16x32_bf16(va, pb, acc[md], 0, 0, 0);
      }
    }
    lsum += __shfl_xor(lsum, 16, 64);
    lsum += __shfl_xor(lsum, 32, 64);
    __syncthreads();
    float* redo = (float*)ks;
    float* redl = (float*)vs;
    if (thalf == 1) {
#pragma unroll
      for (int md = 0; md < 4; md++)
#pragma unroll
        for (int r = 0; r < 4; r++)
          redo[(qsub * 64 + lane) * 16 + md * 4 + r] = acc[md][r];
      redl[qsub * 64 + lane] = lsum;
    }
    __syncthreads();
    if (thalf == 0) {
#pragma unroll
      for (int md = 0; md < 4; md++)
#pragma unroll
        for (int r = 0; r < 4; r++)
          acc[md][r] += redo[(qsub * 64 + lane) * 16 + md * 4 + r];
      lsum += redl[qsub * 64 + lane];
      float rl = 1.0f / lsum;
      u16* ow = pt + qsub * 16 * OTS;
#pragma unroll
      for (int md = 0; md < 4; md++) {
        u64 ok = 0;
#pragma unroll
        for (int r = 0; r < 4; r++)
          ok |= ((u64)f2bf(acc[md][r] * rl)) << (16 * r);
        *(u64*)(ow + l15 * OTS + md * 16 + quad * 4) = ok;
      }
      int qq = lane >> 2, dc = lane & 3;
      uint4 o0 = *(uint4*)(ow + qq * OTS + dc * 16);
      uint4 o1 = *(uint4*)(ow + qq * OTS + dc * 16 + 8);
      size_t orow = (size_t)b * 2048 + q0 + qsub * 16 + qq;
      *(uint4*)(ao + orow * 1024 + h * 64 + dc * 16) = o0;
      *(uint4*)(ao + orow * 1024 + h * 64 + dc * 16 + 8) = o1;
    }
  }
}

// ---------------------------------------------------------------- launch
extern "C" void kernel_launch(void* const* d_in, const int* in_sizes, int n_in,
                              void* d_out, int out_size, void* d_ws,
                              size_t ws_size, hipStream_t stream) {
  const float* x  = (const float*)d_in[0];
  const int* pos  = (const int*)d_in[1];
  const float* Wq = (const float*)d_in[2];
  const float* Wk = (const float*)d_in[3];
  const float* Wv = (const float*)d_in[4];
  const float* Wo = (const float*)d_in[5];
  float* out = (float*)d_out;

  char* ws = (char*)d_ws;
  const size_t MB = 1u << 20;
  u16* xb  = (u16*)(ws);             // 8 MB  [4096][1024] bf16
  u16* wqb = (u16*)(ws + 8 * MB);
  u16* wkb = (u16*)(ws + 10 * MB);
  u16* wvb = (u16*)(ws + 12 * MB);
  u16* wob = (u16*)(ws + 14 * MB);
  u16* qhb = (u16*)(ws + 16 * MB);   // [B][NH][S][HD]  (RoPE'd, Q scaled)
  u16* khb = (u16*)(ws + 24 * MB);
  u16* vtb = (u16*)(ws + 32 * MB);   // [B][NH][HD][S]
  u16* ao  = xb;  // xb dead after gemm_qkv

  cvt_all<<<8192, 256, 0, stream>>>(x, Wq, Wk, Wv, Wo,
                                    xb, wqb, wkb, wvb, wob);
  gemm_qkv<<<dim3(8, 32, 3), 256, 0, stream>>>(xb, wqb, wkb, wvb, pos,
                                               qhb, khb, vtb);
  attn_k<<<1024, 256, 0, stream>>>(qhb, khb, vtb, ao);
  gemm_out<<<dim3(8, 32), 256, 0, stream>>>(ao, wob, out);
}

// Round 6
// 207.523 us; speedup vs baseline: 1.3815x; 1.0148x over previous
//
#include <hip/hip_runtime.h>

// MultiheadSelfAttention w/ RoPE, causal. B=2 S=2048 D=1024 NH=16 HD=64.
// cvt_all (+ global RoPE table precompute) -> gemm_qkv (m97 staging; RoPE
// applied in epilogue from GLOBAL 512KB (cos,sin) table; LDS stays 16KB)
// -> attn (R0-proven 52.9us kernel, untouched) -> gemm_out (split-K=2,
// 512 blocks = 2/CU) -> add_out.
//
// Lessons: R1 forced-occupancy spills; R2 per-tile grid tail; R3/R4 pipeline
// rewrites regress (R0 attn structure is the measured best). R5: RoPE fusion
// works but 32KB per-block LDS table cost 3-blocks/CU occupancy + 512x table
// rebuilds -> table moved to global, built once. gemm_out at 1 block/CU has
// its barrier stalls fully exposed -> split-K=2 doubles residency.

typedef unsigned short u16;
typedef unsigned int   u32;
typedef unsigned long long u64;
using s16x8 = __attribute__((ext_vector_type(8))) short;  // 8 bf16
using f32x4 = __attribute__((ext_vector_type(4))) float;  // 4 fp32 acc

__device__ __forceinline__ u16 f2bf(float f) {
  union { float f; u32 u; } v; v.f = f;
  return (u16)((v.u + 0x7fffu + ((v.u >> 16) & 1u)) >> 16);  // RNE
}
__device__ __forceinline__ float bf2f(u16 h) {
  union { u32 u; float f; } v; v.u = ((u32)h) << 16;
  return v.f;
}

// async 16B global->LDS (DMA; LDS dest = wave-uniform base + lane*16)
__device__ __forceinline__ void gl2lds(const u16* g, u16* l) {
  __builtin_amdgcn_global_load_lds(
      (const __attribute__((address_space(1))) void*)g,
      (__attribute__((address_space(3))) void*)l, 16, 0, 0);
}

// ---------------------------------------------------------------- cvt (fused)
// blocks < 8192: f32->bf16 of x + 4 weights. blocks >= 8192 (256 blocks):
// RoPE table rtab[s*32+pair] = (cos, sin), one entry/thread.
__global__ __launch_bounds__(256) void cvt_all(
    const float* __restrict__ x,
    const float* __restrict__ wq, const float* __restrict__ wk,
    const float* __restrict__ wv, const float* __restrict__ wo,
    u16* __restrict__ xb, u16* __restrict__ wqb, u16* __restrict__ wkb,
    u16* __restrict__ wvb, u16* __restrict__ wob,
    float* __restrict__ rtab, const int* __restrict__ pos) {
  int bid = blockIdx.x;
  if (bid >= 8192) {
    int idx = (bid - 8192) * 256 + threadIdx.x;   // 0..65535
    int s = idx >> 5, pair = idx & 31;
    float p = (float)pos[s];
    float freq = __expf(-0.28782313662425572f * (float)pair);
    float sn, cs;
    sincosf(p * freq, &sn, &cs);
    *(float2*)(rtab + idx * 2) = make_float2(cs, sn);
    return;
  }
  int e = (bid * 256 + threadIdx.x) * 4;
  const float* src; u16* dst; int off;
  const int XN = 4 << 20;
  if (e < XN) { src = x; dst = xb; off = e; }
  else {
    int t = e - XN; int sel = t >> 20; off = t & ((1 << 20) - 1);
    src = sel == 0 ? wq : sel == 1 ? wk : sel == 2 ? wv : wo;
    dst = sel == 0 ? wqb : sel == 1 ? wkb : sel == 2 ? wvb : wob;
  }
  float4 v = *(const float4*)(src + off);
  ushort4 o;
  o.x = f2bf(v.x); o.y = f2bf(v.y); o.z = f2bf(v.z); o.w = f2bf(v.w);
  *(ushort4*)(dst + off) = o;
}

// ---------------------------------------------------------------- GEMM core
// m97 structure: C[128x128] = A[128xK] . W[128xK]^T, bf16, BK=32, K-range
// parameterized for split-K. LDS tiles [128][32] u16 UNPADDED.
__device__ __forceinline__ void gemm_core(
    const u16* __restrict__ A, const u16* __restrict__ W,
    u16* As, u16* Bs, int bm0, int bn0, int kb, int ke, f32x4 (&acc)[4][4]) {
  const int K = 1024;
  int tid = threadIdx.x;
  int wid = tid >> 6, lane = tid & 63, quad = lane >> 4, l15 = lane & 15;
  int wm = (wid >> 1) * 64, wn = (wid & 1) * 64;
  // chunk = row*4 + col8; LDS u16 offset = chunk*8 (row-major [128][32])
  int ch0 = wid * 128 + lane, ch1 = ch0 + 64;
  int r0 = ch0 >> 2, c0 = (ch0 & 3) * 8;
  int r1 = ch1 >> 2, c1 = (ch1 & 3) * 8;
  const u16* Ab = A + (size_t)bm0 * K;
  const u16* Wb = W + (size_t)bn0 * K;
  u16* lA0 = As + wid * 1024; u16* lA1 = lA0 + 512;  // wave-uniform bases
  u16* lB0 = Bs + wid * 1024; u16* lB1 = lB0 + 512;
  for (int k0 = kb; k0 < ke; k0 += 32) {
    __syncthreads();  // prev tile's frag reads done
    gl2lds(Ab + (size_t)r0 * K + k0 + c0, lA0);
    gl2lds(Ab + (size_t)r1 * K + k0 + c1, lA1);
    gl2lds(Wb + (size_t)r0 * K + k0 + c0, lB0);
    gl2lds(Wb + (size_t)r1 * K + k0 + c1, lB1);
    __syncthreads();  // compiler drains vmcnt before barrier
    s16x8 af[4], bf[4];
#pragma unroll
    for (int mi = 0; mi < 4; mi++)
      af[mi] = *(const s16x8*)(As + (wm + mi * 16 + l15) * 32 + quad * 8);
#pragma unroll
    for (int ni = 0; ni < 4; ni++)
      bf[ni] = *(const s16x8*)(Bs + (wn + ni * 16 + l15) * 32 + quad * 8);
#pragma unroll
    for (int mi = 0; mi < 4; mi++)
#pragma unroll
      for (int ni = 0; ni < 4; ni++)
        acc[mi][ni] = __builtin_amdgcn_mfma_f32_16x16x32_bf16(
            af[mi], bf[ni], acc[mi][ni], 0, 0, 0);
  }
}

// ---------------------------------------------------------------- QKV proj
// RoPE fused for z<2. TAB=true: (cos,sin) from global rtab (L2-resident,
// LDS stays 16KB). TAB=false (small-ws fallback): per-block 32KB LDS table
// (R5-proven). Pair partner via __shfl_xor(v,1); Q scaled 1/8.
template <bool TAB>
__global__ __launch_bounds__(256) void gemm_qkv_t(
    const u16* __restrict__ xb,
    const u16* __restrict__ wq, const u16* __restrict__ wk,
    const u16* __restrict__ wv, const int* __restrict__ pos,
    const float* __restrict__ rtab,
    u16* __restrict__ qh, u16* __restrict__ kh, u16* __restrict__ vt) {
  __shared__ __align__(16) u16 As[128 * 32];
  __shared__ __align__(16) u16 Bs[128 * 32];
  __shared__ __align__(16) float tabl[TAB ? 2 : 128 * 32 * 2];
  int z = blockIdx.z;
  const u16* W = (z == 0) ? wq : (z == 1) ? wk : wv;
  int bm0 = blockIdx.y * 128, bn0 = blockIdx.x * 128;
  int tid = threadIdx.x;
  if (!TAB && z < 2) {
    for (int idx = tid; idx < 4096; idx += 256) {
      int rl = idx >> 5, pair = idx & 31;
      int s = (bm0 + rl) & 2047;
      float p = (float)pos[s];
      float freq = __expf(-0.28782313662425572f * (float)pair);
      float sn, cs;
      sincosf(p * freq, &sn, &cs);
      tabl[idx * 2] = cs;
      tabl[idx * 2 + 1] = sn;
    }
  }
  // no barrier needed: gemm_core's first __syncthreads orders tabl writes
  // before any epilogue read.
  f32x4 acc[4][4];
  const f32x4 fz = {0.f, 0.f, 0.f, 0.f};
#pragma unroll
  for (int mi = 0; mi < 4; mi++)
#pragma unroll
    for (int ni = 0; ni < 4; ni++) acc[mi][ni] = fz;
  gemm_core(xb, W, As, Bs, bm0, bn0, 0, 1024, acc);
  int wid = tid >> 6, lane = tid & 63;
  int quad = lane >> 4, l15 = lane & 15;
  int wm = (wid >> 1) * 64, wn = (wid & 1) * 64;
  if (z < 2) {
    u16* dst = (z == 0) ? qh : kh;
    float qs = (z == 0) ? 0.125f : 1.0f;
#pragma unroll
    for (int mi = 0; mi < 4; mi++)
#pragma unroll
      for (int ni = 0; ni < 4; ni++) {
        int col = bn0 + wn + ni * 16 + l15;
        int h = col >> 6, d = col & 63;
        int pairi = d >> 1;
        int odd = d & 1;
#pragma unroll
        for (int r = 0; r < 4; r++) {
          int rl = wm + mi * 16 + quad * 4 + r;   // local row 0..127
          int row = bm0 + rl;
          int b = row >> 11, s = row & 2047;
          float v0 = acc[mi][ni][r];
          float vp = __shfl_xor(v0, 1, 64);       // pair partner (col^1)
          float cs, sn;
          if (TAB) {
            float2 t = *(const float2*)(rtab + (size_t)(s * 32 + pairi) * 2);
            cs = t.x; sn = t.y;
          } else {
            cs = tabl[(rl * 32 + pairi) * 2];
            sn = tabl[(rl * 32 + pairi) * 2 + 1];
          }
          // even d: x1*cs - x2*sn ; odd d: x1*sn + x2*cs
          float o = odd ? (vp * sn + v0 * cs) : (v0 * cs - vp * sn);
          dst[(((size_t)(b * 16 + h)) * 2048 + s) * 64 + d] = f2bf(o * qs);
        }
      }
  } else {
#pragma unroll
    for (int mi = 0; mi < 4; mi++)
#pragma unroll
      for (int ni = 0; ni < 4; ni++) {
        int row0 = bm0 + wm + mi * 16 + quad * 4;
        int col = bn0 + wn + ni * 16 + l15;
        int b = row0 >> 11, s0 = row0 & 2047, h = col >> 6, d = col & 63;
        u64 pk = (u64)f2bf(acc[mi][ni][0]) |
                 ((u64)f2bf(acc[mi][ni][1]) << 16) |
                 ((u64)f2bf(acc[mi][ni][2]) << 32) |
                 ((u64)f2bf(acc[mi][ni][3]) << 48);
        *(u64*)(vt + (((size_t)(b * 16 + h)) * 64 + d) * 2048 + s0) = pk;
      }
  }
}

// ---------------------------------------------------------------- out proj
// split-K=2: grid (8,32,2), z = K-half, partials to pbuf (f32, 2x16MB),
// summed by add_out. 512 blocks = 2 blocks/CU (vs 1 for the monolithic
// version: barrier stalls of one block hide under the other's compute).
__global__ __launch_bounds__(256) void gemm_out_sk(
    const u16* __restrict__ ao, const u16* __restrict__ wo,
    float* __restrict__ pbuf) {
  __shared__ __align__(16) u16 As[128 * 32];
  __shared__ __align__(16) u16 Bs[128 * 32];
  int bm0 = blockIdx.y * 128, bn0 = blockIdx.x * 128;
  int kb = blockIdx.z * 512;
  f32x4 acc[4][4];
  const f32x4 fz = {0.f, 0.f, 0.f, 0.f};
#pragma unroll
  for (int mi = 0; mi < 4; mi++)
#pragma unroll
    for (int ni = 0; ni < 4; ni++) acc[mi][ni] = fz;
  gemm_core(ao, wo, As, Bs, bm0, bn0, kb, kb + 512, acc);
  int tid = threadIdx.x, wid = tid >> 6, lane = tid & 63;
  int quad = lane >> 4, l15 = lane & 15;
  int wm = (wid >> 1) * 64, wn = (wid & 1) * 64;
  float* dst = pbuf + (size_t)blockIdx.z * (4u << 20);
#pragma unroll
  for (int mi = 0; mi < 4; mi++)
#pragma unroll
    for (int ni = 0; ni < 4; ni++)
#pragma unroll
      for (int r = 0; r < 4; r++) {
        int row = bm0 + wm + mi * 16 + quad * 4 + r;
        int col = bn0 + wn + ni * 16 + l15;
        dst[(size_t)row * 1024 + col] = acc[mi][ni][r];
      }
}

__global__ __launch_bounds__(256) void add_out(
    const float* __restrict__ p, float* __restrict__ o) {
  int i = (blockIdx.x * 256 + threadIdx.x) * 4;
  float4 a = *(const float4*)(p + i);
  float4 b = *(const float4*)(p + (4u << 20) + i);
  float4 r;
  r.x = a.x + b.x; r.y = a.y + b.y; r.z = a.z + b.z; r.w = a.w + b.w;
  *(float4*)(o + i) = r;
}

// fallback monolithic out-proj (small workspace)
__global__ __launch_bounds__(256) void gemm_out(
    const u16* __restrict__ ao, const u16* __restrict__ wo,
    float* __restrict__ out) {
  __shared__ __align__(16) u16 As[128 * 32];
  __shared__ __align__(16) u16 Bs[128 * 32];
  int bm0 = blockIdx.y * 128, bn0 = blockIdx.x * 128;
  f32x4 acc[4][4];
  const f32x4 fz = {0.f, 0.f, 0.f, 0.f};
#pragma unroll
  for (int mi = 0; mi < 4; mi++)
#pragma unroll
    for (int ni = 0; ni < 4; ni++) acc[mi][ni] = fz;
  gemm_core(ao, wo, As, Bs, bm0, bn0, 0, 1024, acc);
  int tid = threadIdx.x, wid = tid >> 6, lane = tid & 63;
  int quad = lane >> 4, l15 = lane & 15;
  int wm = (wid >> 1) * 64, wn = (wid & 1) * 64;
#pragma unroll
  for (int mi = 0; mi < 4; mi++)
#pragma unroll
    for (int ni = 0; ni < 4; ni++)
#pragma unroll
      for (int r = 0; r < 4; r++) {
        int row = bm0 + wm + mi * 16 + quad * 4 + r;
        int col = bn0 + wn + ni * 16 + l15;
        out[(size_t)row * 1024 + col] = acc[mi][ni][r];
      }
}

// ---------------------------------------------------------------- attention
// R0-proven version (52.9us): S^T = K.Q^T, O^T = V^T.P^T, no-max softmax.
// Block: 32 q (2 waves qsub) x 64-t tiles split across 2 thalf wave-pairs.
// Grid 1024 = 4 blocks/CU; linear id = bh + 32*pi -> same (b,h) same XCD.
// Register-prefetch pipeline hides K/V staging latency (single LDS buffer).
#define KTS 72
#define VTS 72
#define PTS 40
#define OTS 72

__global__ __launch_bounds__(256, 4) void attn_k(
    const u16* __restrict__ qh, const u16* __restrict__ kh,
    const u16* __restrict__ vt, u16* __restrict__ ao) {
  __shared__ __align__(16) u16 ks[64 * KTS];      // K-tile [t=64][d=64]
  __shared__ __align__(16) u16 vs[64 * VTS];      // V-tile [d=64][t=64]
  __shared__ __align__(16) u16 pt[4 * 16 * PTS];  // per-wave P^T (+ O scratch)
  int bid = blockIdx.x;
  int bh = bid & 31, pi = bid >> 5;
  int b = bh >> 4, h = bh & 15;
  int tid = threadIdx.x, wid = tid >> 6, lane = tid & 63;
  int quad = lane >> 4, l15 = lane & 15;
  int qsub = wid & 1, thalf = wid >> 1;
  const u16* qbase = qh + (size_t)bh * 2048 * 64;
  const u16* kbase = kh + (size_t)bh * 2048 * 64;
  const u16* vbase = vt + (size_t)bh * 64 * 2048;
  u16* ptw = pt + wid * 16 * PTS;
  const f32x4 fz = {0.f, 0.f, 0.f, 0.f};
  int srow = tid >> 2, sc = (tid & 3) * 8;

#pragma unroll
  for (int phase = 0; phase < 2; phase++) {
    int qt = phase ? (63 - pi) : pi;       // q-tile of 32
    int q0 = qt * 32, q0w = q0 + qsub * 16;
    s16x8 qf0 = *(const s16x8*)(qbase + (size_t)(q0w + l15) * 64 + quad * 8);
    s16x8 qf1 = *(const s16x8*)(qbase + (size_t)(q0w + l15) * 64 + 32 + quad * 8);
    f32x4 acc[4];
#pragma unroll
    for (int md = 0; md < 4; md++) acc[md] = fz;
    float lsum = 0.f;
    int qg = q0w + l15;
    int nt = (qt >> 1) + 1;
    uint4 rk0 = *(const uint4*)(kbase + (size_t)srow * 64 + sc);
    uint4 rk1 = *(const uint4*)(kbase + (size_t)srow * 64 + sc + 32);
    uint4 rv0 = *(const uint4*)(vbase + (size_t)srow * 2048 + sc);
    uint4 rv1 = *(const uint4*)(vbase + (size_t)srow * 2048 + sc + 32);
    for (int it = 0; it < nt; it++) {
      __syncthreads();
      *(uint4*)(ks + srow * KTS + sc) = rk0;
      *(uint4*)(ks + srow * KTS + sc + 32) = rk1;
      *(uint4*)(vs + srow * VTS + sc) = rv0;
      *(uint4*)(vs + srow * VTS + sc + 32) = rv1;
      if (it + 1 < nt) {
        int t1 = (it + 1) << 6;
        rk0 = *(const uint4*)(kbase + (size_t)(t1 + srow) * 64 + sc);
        rk1 = *(const uint4*)(kbase + (size_t)(t1 + srow) * 64 + sc + 32);
        rv0 = *(const uint4*)(vbase + (size_t)srow * 2048 + t1 + sc);
        rv1 = *(const uint4*)(vbase + (size_t)srow * 2048 + t1 + sc + 32);
      }
      __syncthreads();
      int t0 = it << 6, tb = thalf * 32;
      bool diag = (it == nt - 1);
#pragma unroll
      for (int mt = 0; mt < 2; mt++) {
        int krow = tb + mt * 16 + l15;
        s16x8 ka0 = *(const s16x8*)(ks + krow * KTS + quad * 8);
        s16x8 ka1 = *(const s16x8*)(ks + krow * KTS + 32 + quad * 8);
        f32x4 st = __builtin_amdgcn_mfma_f32_16x16x32_bf16(ka0, qf0, fz, 0, 0, 0);
        st = __builtin_amdgcn_mfma_f32_16x16x32_bf16(ka1, qf1, st, 0, 0, 0);
        u64 pk = 0;
#pragma unroll
        for (int r = 0; r < 4; r++) {
          float p = __expf(st[r]);
          if (diag) {
            int tg = t0 + tb + mt * 16 + quad * 4 + r;
            if (tg > qg) p = 0.f;
          }
          lsum += p;
          pk |= ((u64)f2bf(p)) << (16 * r);
        }
        *(u64*)(ptw + l15 * PTS + mt * 16 + quad * 4) = pk;
      }
      s16x8 pb = *(const s16x8*)(ptw + l15 * PTS + quad * 8);
#pragma unroll
      for (int md = 0; md < 4; md++) {
        s16x8 va = *(const s16x8*)(vs + (md * 16 + l15) * VTS + tb + quad * 8);
        acc[md] = __builtin_amdgcn_mfma_f32_16x16x32_bf16(va, pb, acc[md], 0, 0, 0);
      }
    }
    lsum += __shfl_xor(lsum, 16, 64);
    lsum += __shfl_xor(lsum, 32, 64);
    __syncthreads();
    float* redo = (float*)ks;
    float* redl = (float*)vs;
    if (thalf == 1) {
#pragma unroll
      for (int md = 0; md < 4; md++)
#pragma unroll
        for (int r = 0; r < 4; r++)
          redo[(qsub * 64 + lane) * 16 + md * 4 + r] = acc[md][r];
      redl[qsub * 64 + lane] = lsum;
    }
    __syncthreads();
    if (thalf == 0) {
#pragma unroll
      for (int md = 0; md < 4; md++)
#pragma unroll
        for (int r = 0; r < 4; r++)
          acc[md][r] += redo[(qsub * 64 + lane) * 16 + md * 4 + r];
      lsum += redl[qsub * 64 + lane];
      float rl = 1.0f / lsum;
      u16* ow = pt + qsub * 16 * OTS;
#pragma unroll
      for (int md = 0; md < 4; md++) {
        u64 ok = 0;
#pragma unroll
        for (int r = 0; r < 4; r++)
          ok |= ((u64)f2bf(acc[md][r] * rl)) << (16 * r);
        *(u64*)(ow + l15 * OTS + md * 16 + quad * 4) = ok;
      }
      int qq = lane >> 2, dc = lane & 3;
      uint4 o0 = *(uint4*)(ow + qq * OTS + dc * 16);
      uint4 o1 = *(uint4*)(ow + qq * OTS + dc * 16 + 8);
      size_t orow = (size_t)b * 2048 + q0 + qsub * 16 + qq;
      *(uint4*)(ao + orow * 1024 + h * 64 + dc * 16) = o0;
      *(uint4*)(ao + orow * 1024 + h * 64 + dc * 16 + 8) = o1;
    }
  }
}

// ---------------------------------------------------------------- launch
extern "C" void kernel_launch(void* const* d_in, const int* in_sizes, int n_in,
                              void* d_out, int out_size, void* d_ws,
                              size_t ws_size, hipStream_t stream) {
  const float* x  = (const float*)d_in[0];
  const int* pos  = (const int*)d_in[1];
  const float* Wq = (const float*)d_in[2];
  const float* Wk = (const float*)d_in[3];
  const float* Wv = (const float*)d_in[4];
  const float* Wo = (const float*)d_in[5];
  float* out = (float*)d_out;

  char* ws = (char*)d_ws;
  const size_t MB = 1u << 20;
  u16* xb  = (u16*)(ws);             // 8 MB  [4096][1024] bf16
  u16* wqb = (u16*)(ws + 8 * MB);
  u16* wkb = (u16*)(ws + 10 * MB);
  u16* wvb = (u16*)(ws + 12 * MB);
  u16* wob = (u16*)(ws + 14 * MB);
  u16* qhb = (u16*)(ws + 16 * MB);   // [B][NH][S][HD]  (RoPE'd, Q scaled)
  u16* khb = (u16*)(ws + 24 * MB);
  u16* vtb = (u16*)(ws + 32 * MB);   // [B][NH][HD][S]
  float* rtab = (float*)(ws + 40 * MB);  // 512 KB RoPE (cos,sin) table
  float* pbuf = (float*)(ws + 41 * MB);  // 32 MB split-K partials
  u16* ao  = xb;  // xb dead after gemm_qkv

  bool tabok = ws_size >= 41 * MB;   // rtab fits
  bool skok  = ws_size >= 73 * MB;   // pbuf fits

  cvt_all<<<tabok ? 8448 : 8192, 256, 0, stream>>>(
      x, Wq, Wk, Wv, Wo, xb, wqb, wkb, wvb, wob, rtab, pos);
  if (tabok)
    gemm_qkv_t<true><<<dim3(8, 32, 3), 256, 0, stream>>>(
        xb, wqb, wkb, wvb, pos, rtab, qhb, khb, vtb);
  else
    gemm_qkv_t<false><<<dim3(8, 32, 3), 256, 0, stream>>>(
        xb, wqb, wkb, wvb, pos, rtab, qhb, khb, vtb);
  attn_k<<<1024, 256, 0, stream>>>(qhb, khb, vtb, ao);
  if (skok) {
    gemm_out_sk<<<dim3(8, 32, 2), 256, 0, stream>>>(ao, wob, pbuf);
    add_out<<<4096, 256, 0, stream>>>(pbuf, out);
  } else {
    gemm_out<<<dim3(8, 32), 256, 0, stream>>>(ao, wob, out);
  }
}

// Round 7
// 195.953 us; speedup vs baseline: 1.4631x; 1.0590x over previous
//
#include <hip/hip_runtime.h>

// MultiheadSelfAttention w/ RoPE, causal. B=2 S=2048 D=1024 NH=16 HD=64.
// cvt_all (+ global RoPE table) -> gemm_qkv (m97 staging; XCD-swizzled grid;
// RoPE epilogue w/ LDS-transposed PACKED uint4 stores) -> attn (R0 pipeline,
// QBLK=64 x 8 waves: half the staging/barriers per FLOP) -> gemm_out
// (split-K=2, XCD-swizzled) -> add_out.
//
// Lessons: R1 forced-occupancy spills; R2 per-tile grid tail; R3/R4 attn
// pipeline rewrites regress (R0 per-wave pipeline is the measured best —
// kept verbatim here, only wave/block geometry changed). R6: qkv FETCH 70MB
// = 8 sibling blocks on 8 different XCDs (swizzle fixes); 64 scalar u16
// stores/thread in qkv epilogue (LDS round-trip packs to 8 uint4).

typedef unsigned short u16;
typedef unsigned int   u32;
typedef unsigned long long u64;
using s16x8 = __attribute__((ext_vector_type(8))) short;  // 8 bf16
using f32x4 = __attribute__((ext_vector_type(4))) float;  // 4 fp32 acc

__device__ __forceinline__ u16 f2bf(float f) {
  union { float f; u32 u; } v; v.f = f;
  return (u16)((v.u + 0x7fffu + ((v.u >> 16) & 1u)) >> 16);  // RNE
}
__device__ __forceinline__ float bf2f(u16 h) {
  union { u32 u; float f; } v; v.u = ((u32)h) << 16;
  return v.f;
}

// async 16B global->LDS (DMA; LDS dest = wave-uniform base + lane*16)
__device__ __forceinline__ void gl2lds(const u16* g, u16* l) {
  __builtin_amdgcn_global_load_lds(
      (const __attribute__((address_space(1))) void*)g,
      (__attribute__((address_space(3))) void*)l, 16, 0, 0);
}

// ---------------------------------------------------------------- cvt (fused)
// blocks < 8192: f32->bf16 of x + 4 weights. blocks >= 8192 (256 blocks):
// RoPE table rtab[s*32+pair] = (cos, sin), one entry/thread.
__global__ __launch_bounds__(256) void cvt_all(
    const float* __restrict__ x,
    const float* __restrict__ wq, const float* __restrict__ wk,
    const float* __restrict__ wv, const float* __restrict__ wo,
    u16* __restrict__ xb, u16* __restrict__ wqb, u16* __restrict__ wkb,
    u16* __restrict__ wvb, u16* __restrict__ wob,
    float* __restrict__ rtab, const int* __restrict__ pos) {
  int bid = blockIdx.x;
  if (bid >= 8192) {
    int idx = (bid - 8192) * 256 + threadIdx.x;   // 0..65535
    int s = idx >> 5, pair = idx & 31;
    float p = (float)pos[s];
    float freq = __expf(-0.28782313662425572f * (float)pair);
    float sn, cs;
    sincosf(p * freq, &sn, &cs);
    *(float2*)(rtab + idx * 2) = make_float2(cs, sn);
    return;
  }
  int e = (bid * 256 + threadIdx.x) * 4;
  const float* src; u16* dst; int off;
  const int XN = 4 << 20;
  if (e < XN) { src = x; dst = xb; off = e; }
  else {
    int t = e - XN; int sel = t >> 20; off = t & ((1 << 20) - 1);
    src = sel == 0 ? wq : sel == 1 ? wk : sel == 2 ? wv : wo;
    dst = sel == 0 ? wqb : sel == 1 ? wkb : sel == 2 ? wvb : wob;
  }
  float4 v = *(const float4*)(src + off);
  ushort4 o;
  o.x = f2bf(v.x); o.y = f2bf(v.y); o.z = f2bf(v.z); o.w = f2bf(v.w);
  *(ushort4*)(dst + off) = o;
}

// ---------------------------------------------------------------- GEMM core
// m97 structure: C[128x128] = A[128xK] . W[128xK]^T, bf16, BK=32, K-range
// parameterized for split-K. LDS tiles [128][32] u16 UNPADDED.
__device__ __forceinline__ void gemm_core(
    const u16* __restrict__ A, const u16* __restrict__ W,
    u16* As, u16* Bs, int bm0, int bn0, int kb, int ke, f32x4 (&acc)[4][4]) {
  const int K = 1024;
  int tid = threadIdx.x;
  int wid = tid >> 6, lane = tid & 63, quad = lane >> 4, l15 = lane & 15;
  int wm = (wid >> 1) * 64, wn = (wid & 1) * 64;
  // chunk = row*4 + col8; LDS u16 offset = chunk*8 (row-major [128][32])
  int ch0 = wid * 128 + lane, ch1 = ch0 + 64;
  int r0 = ch0 >> 2, c0 = (ch0 & 3) * 8;
  int r1 = ch1 >> 2, c1 = (ch1 & 3) * 8;
  const u16* Ab = A + (size_t)bm0 * K;
  const u16* Wb = W + (size_t)bn0 * K;
  u16* lA0 = As + wid * 1024; u16* lA1 = lA0 + 512;  // wave-uniform bases
  u16* lB0 = Bs + wid * 1024; u16* lB1 = lB0 + 512;
  for (int k0 = kb; k0 < ke; k0 += 32) {
    __syncthreads();  // prev tile's frag reads done
    gl2lds(Ab + (size_t)r0 * K + k0 + c0, lA0);
    gl2lds(Ab + (size_t)r1 * K + k0 + c1, lA1);
    gl2lds(Wb + (size_t)r0 * K + k0 + c0, lB0);
    gl2lds(Wb + (size_t)r1 * K + k0 + c1, lB1);
    __syncthreads();  // compiler drains vmcnt before barrier
    s16x8 af[4], bf[4];
#pragma unroll
    for (int mi = 0; mi < 4; mi++)
      af[mi] = *(const s16x8*)(As + (wm + mi * 16 + l15) * 32 + quad * 8);
#pragma unroll
    for (int ni = 0; ni < 4; ni++)
      bf[ni] = *(const s16x8*)(Bs + (wn + ni * 16 + l15) * 32 + quad * 8);
#pragma unroll
    for (int mi = 0; mi < 4; mi++)
#pragma unroll
      for (int ni = 0; ni < 4; ni++)
        acc[mi][ni] = __builtin_amdgcn_mfma_f32_16x16x32_bf16(
            af[mi], bf[ni], acc[mi][ni], 0, 0, 0);
  }
}

// ---------------------------------------------------------------- QKV proj
// XCD-swizzled grid: flat id -> nid = (id%8)*96 + id/8 (768%8==0, bijective)
// so the 8 blocks sharing an A-panel land on ONE XCD's L2.
// RoPE fused for z<2 from global rtab. Epilogue: RoPE'd bf16 tile staged in
// ob[128][136] LDS, stored back as 8 coalesced uint4/thread (was 64 scalar
// u16 stores/thread). V path (z=2) keeps the packed-u64 direct store.
template <bool TAB>
__global__ __launch_bounds__(256) void gemm_qkv_t(
    const u16* __restrict__ xb,
    const u16* __restrict__ wq, const u16* __restrict__ wk,
    const u16* __restrict__ wv, const int* __restrict__ pos,
    const float* __restrict__ rtab,
    u16* __restrict__ qh, u16* __restrict__ kh, u16* __restrict__ vt) {
  __shared__ __align__(16) u16 As[128 * 32];
  __shared__ __align__(16) u16 Bs[128 * 32];
  __shared__ __align__(16) u16 ob[128 * 136];   // 34816B epilogue stage
  __shared__ __align__(16) float tabl[TAB ? 2 : 128 * 32 * 2];
  int id = blockIdx.x + 8 * blockIdx.y + 256 * blockIdx.z;
  int nid = (id & 7) * 96 + (id >> 3);          // XCD swizzle
  int bx = nid & 7, by = (nid >> 3) & 31, z = nid >> 8;
  const u16* W = (z == 0) ? wq : (z == 1) ? wk : wv;
  int bm0 = by * 128, bn0 = bx * 128;
  int tid = threadIdx.x;
  if (!TAB && z < 2) {
    for (int idx = tid; idx < 4096; idx += 256) {
      int rl = idx >> 5, pair = idx & 31;
      int s = (bm0 + rl) & 2047;
      float p = (float)pos[s];
      float freq = __expf(-0.28782313662425572f * (float)pair);
      float sn, cs;
      sincosf(p * freq, &sn, &cs);
      tabl[idx * 2] = cs;
      tabl[idx * 2 + 1] = sn;
    }
  }
  f32x4 acc[4][4];
  const f32x4 fz = {0.f, 0.f, 0.f, 0.f};
#pragma unroll
  for (int mi = 0; mi < 4; mi++)
#pragma unroll
    for (int ni = 0; ni < 4; ni++) acc[mi][ni] = fz;
  gemm_core(xb, W, As, Bs, bm0, bn0, 0, 1024, acc);
  int wid = tid >> 6, lane = tid & 63;
  int quad = lane >> 4, l15 = lane & 15;
  int wm = (wid >> 1) * 64, wn = (wid & 1) * 64;
  if (z < 2) {
    u16* dst = (z == 0) ? qh : kh;
    float qs = (z == 0) ? 0.125f : 1.0f;
    // phase 1: RoPE + cvt into ob (per-thread own values, no hazard)
#pragma unroll
    for (int mi = 0; mi < 4; mi++)
#pragma unroll
      for (int ni = 0; ni < 4; ni++) {
        int col = wn + ni * 16 + l15;          // local col 0..127
        int d = (bn0 + col) & 63;
        int pairi = d >> 1, odd = d & 1;
#pragma unroll
        for (int r = 0; r < 4; r++) {
          int rl = wm + mi * 16 + quad * 4 + r;  // local row 0..127
          int s = (bm0 + rl) & 2047;
          float v0 = acc[mi][ni][r];
          float vp = __shfl_xor(v0, 1, 64);      // pair partner (col^1)
          float cs, sn;
          if (TAB) {
            float2 t = *(const float2*)(rtab + (size_t)(s * 32 + pairi) * 2);
            cs = t.x; sn = t.y;
          } else {
            cs = tabl[(rl * 32 + pairi) * 2];
            sn = tabl[(rl * 32 + pairi) * 2 + 1];
          }
          float o = odd ? (vp * sn + v0 * cs) : (v0 * cs - vp * sn);
          ob[rl * 136 + col] = f2bf(o * qs);
        }
      }
    __syncthreads();
    // phase 2: coalesced packed store. 128 rows x 16 segs of 16B; 8/thread.
#pragma unroll
    for (int k2 = 0; k2 < 8; k2++) {
      int idx = tid + 256 * k2;                // 0..2047
      int row = idx >> 4, seg = idx & 15;
      uint4 w = *(const uint4*)(ob + row * 136 + seg * 8);
      int grow = bm0 + row;
      int b2 = grow >> 11, s2 = grow & 2047;
      int gc = bn0 + seg * 8;
      int h2 = gc >> 6, d2 = gc & 63;
      *(uint4*)(dst + (((size_t)(b2 * 16 + h2)) * 2048 + s2) * 64 + d2) = w;
    }
  } else {
#pragma unroll
    for (int mi = 0; mi < 4; mi++)
#pragma unroll
      for (int ni = 0; ni < 4; ni++) {
        int row0 = bm0 + wm + mi * 16 + quad * 4;
        int col = bn0 + wn + ni * 16 + l15;
        int b = row0 >> 11, s0 = row0 & 2047, h = col >> 6, d = col & 63;
        u64 pk = (u64)f2bf(acc[mi][ni][0]) |
                 ((u64)f2bf(acc[mi][ni][1]) << 16) |
                 ((u64)f2bf(acc[mi][ni][2]) << 32) |
                 ((u64)f2bf(acc[mi][ni][3]) << 48);
        *(u64*)(vt + (((size_t)(b * 16 + h)) * 64 + d) * 2048 + s0) = pk;
      }
  }
}

// ---------------------------------------------------------------- out proj
// split-K=2, XCD-swizzled (512%8==0): grid (8,32,2), partials to pbuf.
__global__ __launch_bounds__(256) void gemm_out_sk(
    const u16* __restrict__ ao, const u16* __restrict__ wo,
    float* __restrict__ pbuf) {
  __shared__ __align__(16) u16 As[128 * 32];
  __shared__ __align__(16) u16 Bs[128 * 32];
  int id = blockIdx.x + 8 * blockIdx.y + 256 * blockIdx.z;
  int nid = (id & 7) * 64 + (id >> 3);
  int bx = nid & 7, by = (nid >> 3) & 31, z = nid >> 8;
  int bm0 = by * 128, bn0 = bx * 128;
  int kb = z * 512;
  f32x4 acc[4][4];
  const f32x4 fz = {0.f, 0.f, 0.f, 0.f};
#pragma unroll
  for (int mi = 0; mi < 4; mi++)
#pragma unroll
    for (int ni = 0; ni < 4; ni++) acc[mi][ni] = fz;
  gemm_core(ao, wo, As, Bs, bm0, bn0, kb, kb + 512, acc);
  int tid = threadIdx.x, wid = tid >> 6, lane = tid & 63;
  int quad = lane >> 4, l15 = lane & 15;
  int wm = (wid >> 1) * 64, wn = (wid & 1) * 64;
  float* dst = pbuf + (size_t)z * (4u << 20);
#pragma unroll
  for (int mi = 0; mi < 4; mi++)
#pragma unroll
    for (int ni = 0; ni < 4; ni++)
#pragma unroll
      for (int r = 0; r < 4; r++) {
        int row = bm0 + wm + mi * 16 + quad * 4 + r;
        int col = bn0 + wn + ni * 16 + l15;
        dst[(size_t)row * 1024 + col] = acc[mi][ni][r];
      }
}

__global__ __launch_bounds__(256) void add_out(
    const float* __restrict__ p, float* __restrict__ o) {
  int i = (blockIdx.x * 256 + threadIdx.x) * 4;
  float4 a = *(const float4*)(p + i);
  float4 b = *(const float4*)(p + (4u << 20) + i);
  float4 r;
  r.x = a.x + b.x; r.y = a.y + b.y; r.z = a.z + b.z; r.w = a.w + b.w;
  *(float4*)(o + i) = r;
}

// fallback monolithic out-proj (small workspace)
__global__ __launch_bounds__(256) void gemm_out(
    const u16* __restrict__ ao, const u16* __restrict__ wo,
    float* __restrict__ out) {
  __shared__ __align__(16) u16 As[128 * 32];
  __shared__ __align__(16) u16 Bs[128 * 32];
  int bm0 = blockIdx.y * 128, bn0 = blockIdx.x * 128;
  f32x4 acc[4][4];
  const f32x4 fz = {0.f, 0.f, 0.f, 0.f};
#pragma unroll
  for (int mi = 0; mi < 4; mi++)
#pragma unroll
    for (int ni = 0; ni < 4; ni++) acc[mi][ni] = fz;
  gemm_core(ao, wo, As, Bs, bm0, bn0, 0, 1024, acc);
  int tid = threadIdx.x, wid = tid >> 6, lane = tid & 63;
  int quad = lane >> 4, l15 = lane & 15;
  int wm = (wid >> 1) * 64, wn = (wid & 1) * 64;
#pragma unroll
  for (int mi = 0; mi < 4; mi++)
#pragma unroll
    for (int ni = 0; ni < 4; ni++)
#pragma unroll
      for (int r = 0; r < 4; r++) {
        int row = bm0 + wm + mi * 16 + quad * 4 + r;
        int col = bn0 + wn + ni * 16 + l15;
        out[(size_t)row * 1024 + col] = acc[mi][ni][r];
      }
}

// ---------------------------------------------------------------- attention
// R0 per-wave pipeline kept VERBATIM; geometry widened: QBLK=64 via 8 waves
// (512 thr), 4 qsub x 2 thalf. Same 16 waves/CU (2 blocks x 8 waves), same
// per-wave work per iter, but HALF the staged bytes / barriers / K,V global
// re-reads per FLOP. Grid 512 = 32 bh x 16 pi; pairing (pi, 31-pi) -> 33
// uniform iters/block. bh = bid&31 keeps each (b,h)'s K/V on one XCD.
#define KTS 72
#define VTS 72
#define PTS 40
#define OTS 72

__global__ __launch_bounds__(512, 4) void attn_k(
    const u16* __restrict__ qh, const u16* __restrict__ kh,
    const u16* __restrict__ vt, u16* __restrict__ ao) {
  __shared__ __align__(16) u16 kv[64 * KTS + 64 * VTS];  // K tile then V tile
  __shared__ __align__(16) u16 pt[8 * 16 * PTS];         // per-wave P^T + ow
  __shared__ __align__(16) float redl2[256];             // lsum partials
  u16* ks = kv;
  u16* vs = kv + 64 * KTS;
  int bid = blockIdx.x;
  int bh = bid & 31, pi = bid >> 5;        // pi 0..15
  int b = bh >> 4, h = bh & 15;
  int tid = threadIdx.x, wid = tid >> 6, lane = tid & 63;
  int quad = lane >> 4, l15 = lane & 15;
  int qsub = wid & 3, thalf = wid >> 2;
  const u16* qbase = qh + (size_t)bh * 2048 * 64;
  const u16* kbase = kh + (size_t)bh * 2048 * 64;
  const u16* vbase = vt + (size_t)bh * 64 * 2048;
  u16* ptw = pt + wid * 16 * PTS;
  const f32x4 fz = {0.f, 0.f, 0.f, 0.f};
  int srow = tid >> 3, sc = (tid & 7) * 8;  // 512 thr: 1 uint4/thread/array
  int tb = thalf * 32;

#pragma unroll
  for (int phase = 0; phase < 2; phase++) {
    int qt = phase ? (31 - pi) : pi;       // q-tile of 64
    int q0 = qt * 64, q0w = q0 + qsub * 16;
    s16x8 qf0 = *(const s16x8*)(qbase + (size_t)(q0w + l15) * 64 + quad * 8);
    s16x8 qf1 = *(const s16x8*)(qbase + (size_t)(q0w + l15) * 64 + 32 + quad * 8);
    f32x4 acc[4];
#pragma unroll
    for (int md = 0; md < 4; md++) acc[md] = fz;
    float lsum = 0.f;
    int qg = q0w + l15;
    int nt = qt + 1;
    uint4 rk0 = *(const uint4*)(kbase + (size_t)srow * 64 + sc);
    uint4 rv0 = *(const uint4*)(vbase + (size_t)srow * 2048 + sc);
    for (int it = 0; it < nt; it++) {
      __syncthreads();
      *(uint4*)(ks + srow * KTS + sc) = rk0;
      *(uint4*)(vs + srow * VTS + sc) = rv0;
      if (it + 1 < nt) {
        int t1 = (it + 1) << 6;
        rk0 = *(const uint4*)(kbase + (size_t)(t1 + srow) * 64 + sc);
        rv0 = *(const uint4*)(vbase + (size_t)srow * 2048 + t1 + sc);
      }
      __syncthreads();
      int t0 = it << 6;
      bool diag = (it == nt - 1);
#pragma unroll
      for (int mt = 0; mt < 2; mt++) {
        int krow = tb + mt * 16 + l15;
        s16x8 ka0 = *(const s16x8*)(ks + krow * KTS + quad * 8);
        s16x8 ka1 = *(const s16x8*)(ks + krow * KTS + 32 + quad * 8);
        f32x4 st = __builtin_amdgcn_mfma_f32_16x16x32_bf16(ka0, qf0, fz, 0, 0, 0);
        st = __builtin_amdgcn_mfma_f32_16x16x32_bf16(ka1, qf1, st, 0, 0, 0);
        u64 pk = 0;
#pragma unroll
        for (int r = 0; r < 4; r++) {
          float p = __expf(st[r]);
          if (diag) {
            int tg = t0 + tb + mt * 16 + quad * 4 + r;
            if (tg > qg) p = 0.f;
          }
          lsum += p;
          pk |= ((u64)f2bf(p)) << (16 * r);
        }
        *(u64*)(ptw + l15 * PTS + mt * 16 + quad * 4) = pk;
      }
      s16x8 pb = *(const s16x8*)(ptw + l15 * PTS + quad * 8);
#pragma unroll
      for (int md = 0; md < 4; md++) {
        s16x8 va = *(const s16x8*)(vs + (md * 16 + l15) * VTS + tb + quad * 8);
        acc[md] = __builtin_amdgcn_mfma_f32_16x16x32_bf16(va, pb, acc[md], 0, 0, 0);
      }
    }
    lsum += __shfl_xor(lsum, 16, 64);
    lsum += __shfl_xor(lsum, 32, 64);
    __syncthreads();
    float* redo = (float*)kv;              // 256 lanes x 16 f32 = 16KB <= kv
    if (thalf == 1) {
#pragma unroll
      for (int md = 0; md < 4; md++)
#pragma unroll
        for (int r = 0; r < 4; r++)
          redo[(qsub * 64 + lane) * 16 + md * 4 + r] = acc[md][r];
      redl2[qsub * 64 + lane] = lsum;
    }
    __syncthreads();
    if (thalf == 0) {
#pragma unroll
      for (int md = 0; md < 4; md++)
#pragma unroll
        for (int r = 0; r < 4; r++)
          acc[md][r] += redo[(qsub * 64 + lane) * 16 + md * 4 + r];
      lsum += redl2[qsub * 64 + lane];
      float rl = 1.0f / lsum;
      u16* ow = pt + qsub * 16 * OTS;      // 4 x 2304B <= pt (10240B)
#pragma unroll
      for (int md = 0; md < 4; md++) {
        u64 ok = 0;
#pragma unroll
        for (int r = 0; r < 4; r++)
          ok |= ((u64)f2bf(acc[md][r] * rl)) << (16 * r);
        *(u64*)(ow + l15 * OTS + md * 16 + quad * 4) = ok;
      }
      int qq = lane >> 2, dc = lane & 3;
      uint4 o0 = *(uint4*)(ow + qq * OTS + dc * 16);
      uint4 o1 = *(uint4*)(ow + qq * OTS + dc * 16 + 8);
      size_t orow = (size_t)b * 2048 + q0 + qsub * 16 + qq;
      *(uint4*)(ao + orow * 1024 + h * 64 + dc * 16) = o0;
      *(uint4*)(ao + orow * 1024 + h * 64 + dc * 16 + 8) = o1;
    }
  }
}

// ---------------------------------------------------------------- launch
extern "C" void kernel_launch(void* const* d_in, const int* in_sizes, int n_in,
                              void* d_out, int out_size, void* d_ws,
                              size_t ws_size, hipStream_t stream) {
  const float* x  = (const float*)d_in[0];
  const int* pos  = (const int*)d_in[1];
  const float* Wq = (const float*)d_in[2];
  const float* Wk = (const float*)d_in[3];
  const float* Wv = (const float*)d_in[4];
  const float* Wo = (const float*)d_in[5];
  float* out = (float*)d_out;

  char* ws = (char*)d_ws;
  const size_t MB = 1u << 20;
  u16* xb  = (u16*)(ws);             // 8 MB  [4096][1024] bf16
  u16* wqb = (u16*)(ws + 8 * MB);
  u16* wkb = (u16*)(ws + 10 * MB);
  u16* wvb = (u16*)(ws + 12 * MB);
  u16* wob = (u16*)(ws + 14 * MB);
  u16* qhb = (u16*)(ws + 16 * MB);   // [B][NH][S][HD]  (RoPE'd, Q scaled)
  u16* khb = (u16*)(ws + 24 * MB);
  u16* vtb = (u16*)(ws + 32 * MB);   // [B][NH][HD][S]
  float* rtab = (float*)(ws + 40 * MB);  // 512 KB RoPE (cos,sin) table
  float* pbuf = (float*)(ws + 41 * MB);  // 32 MB split-K partials
  u16* ao  = xb;  // xb dead after gemm_qkv

  bool tabok = ws_size >= 41 * MB;   // rtab fits
  bool skok  = ws_size >= 73 * MB;   // pbuf fits

  cvt_all<<<tabok ? 8448 : 8192, 256, 0, stream>>>(
      x, Wq, Wk, Wv, Wo, xb, wqb, wkb, wvb, wob, rtab, pos);
  if (tabok)
    gemm_qkv_t<true><<<dim3(8, 32, 3), 256, 0, stream>>>(
        xb, wqb, wkb, wvb, pos, rtab, qhb, khb, vtb);
  else
    gemm_qkv_t<false><<<dim3(8, 32, 3), 256, 0, stream>>>(
        xb, wqb, wkb, wvb, pos, rtab, qhb, khb, vtb);
  attn_k<<<512, 512, 0, stream>>>(qhb, khb, vtb, ao);
  if (skok) {
    gemm_out_sk<<<dim3(8, 32, 2), 256, 0, stream>>>(ao, wob, pbuf);
    add_out<<<4096, 256, 0, stream>>>(pbuf, out);
  } else {
    gemm_out<<<dim3(8, 32), 256, 0, stream>>>(ao, wob, out);
  }
}

// Round 8
// 177.422 us; speedup vs baseline: 1.6159x; 1.1044x over previous
//
#include <hip/hip_runtime.h>

// MultiheadSelfAttention w/ RoPE, causal. B=2 S=2048 D=1024 NH=16 HD=64.
// cvt_all (+ global RoPE table) -> gemm_qkv (m97 staging; XCD swizzle;
// Q/K use SWAPPED MFMA operands so the output fragment is s-in-lane /
// d-in-reg: RoPE pairs are THREAD-LOCAL, stores pack to u64, no LDS
// transpose) -> attn (R7: R0 pipeline, QBLK=64 x 8 waves) -> gemm_out
// (N=64 tiles, 512 blocks = 2/CU, no split-K partial traffic).
//
// Lessons: R1 forced-occupancy spills; R2 per-tile grid tail; R3/R4 attn
// pipeline rewrites regress; R6/R7: XCD swizzle cuts FETCH 70->31MB; qkv
// epilogue cost was the LDS transpose + shfl (operand swap deletes both).

typedef unsigned short u16;
typedef unsigned int   u32;
typedef unsigned long long u64;
using s16x8 = __attribute__((ext_vector_type(8))) short;  // 8 bf16
using f32x4 = __attribute__((ext_vector_type(4))) float;  // 4 fp32 acc

__device__ __forceinline__ u16 f2bf(float f) {
  union { float f; u32 u; } v; v.f = f;
  return (u16)((v.u + 0x7fffu + ((v.u >> 16) & 1u)) >> 16);  // RNE
}
__device__ __forceinline__ float bf2f(u16 h) {
  union { u32 u; float f; } v; v.u = ((u32)h) << 16;
  return v.f;
}

// async 16B global->LDS (DMA; LDS dest = wave-uniform base + lane*16)
__device__ __forceinline__ void gl2lds(const u16* g, u16* l) {
  __builtin_amdgcn_global_load_lds(
      (const __attribute__((address_space(1))) void*)g,
      (__attribute__((address_space(3))) void*)l, 16, 0, 0);
}

// ---------------------------------------------------------------- cvt (fused)
__global__ __launch_bounds__(256) void cvt_all(
    const float* __restrict__ x,
    const float* __restrict__ wq, const float* __restrict__ wk,
    const float* __restrict__ wv, const float* __restrict__ wo,
    u16* __restrict__ xb, u16* __restrict__ wqb, u16* __restrict__ wkb,
    u16* __restrict__ wvb, u16* __restrict__ wob,
    float* __restrict__ rtab, const int* __restrict__ pos) {
  int bid = blockIdx.x;
  if (bid >= 8192) {
    int idx = (bid - 8192) * 256 + threadIdx.x;   // 0..65535
    int s = idx >> 5, pair = idx & 31;
    float p = (float)pos[s];
    float freq = __expf(-0.28782313662425572f * (float)pair);
    float sn, cs;
    sincosf(p * freq, &sn, &cs);
    *(float2*)(rtab + idx * 2) = make_float2(cs, sn);
    return;
  }
  int e = (bid * 256 + threadIdx.x) * 4;
  const float* src; u16* dst; int off;
  const int XN = 4 << 20;
  if (e < XN) { src = x; dst = xb; off = e; }
  else {
    int t = e - XN; int sel = t >> 20; off = t & ((1 << 20) - 1);
    src = sel == 0 ? wq : sel == 1 ? wk : sel == 2 ? wv : wo;
    dst = sel == 0 ? wqb : sel == 1 ? wkb : sel == 2 ? wvb : wob;
  }
  float4 v = *(const float4*)(src + off);
  ushort4 o;
  o.x = f2bf(v.x); o.y = f2bf(v.y); o.z = f2bf(v.z); o.w = f2bf(v.w);
  *(ushort4*)(dst + off) = o;
}

// ---------------------------------------------------------------- GEMM core
// m97 structure: C[128x128] = A[128xK] . W[128xK]^T, bf16, BK=32.
// SWAP=true: acc[mi][ni] = W-row in (quad*4+r), A-row in l15 (C^T fragment).
template <bool SWAP>
__device__ __forceinline__ void gemm_core(
    const u16* __restrict__ A, const u16* __restrict__ W,
    u16* As, u16* Bs, int bm0, int bn0, f32x4 (&acc)[4][4]) {
  const int K = 1024;
  int tid = threadIdx.x;
  int wid = tid >> 6, lane = tid & 63, quad = lane >> 4, l15 = lane & 15;
  int wm = (wid >> 1) * 64, wn = (wid & 1) * 64;
  int ch0 = wid * 128 + lane, ch1 = ch0 + 64;
  int r0 = ch0 >> 2, c0 = (ch0 & 3) * 8;
  int r1 = ch1 >> 2, c1 = (ch1 & 3) * 8;
  const u16* Ab = A + (size_t)bm0 * K;
  const u16* Wb = W + (size_t)bn0 * K;
  u16* lA0 = As + wid * 1024; u16* lA1 = lA0 + 512;
  u16* lB0 = Bs + wid * 1024; u16* lB1 = lB0 + 512;
  for (int k0 = 0; k0 < K; k0 += 32) {
    __syncthreads();
    gl2lds(Ab + (size_t)r0 * K + k0 + c0, lA0);
    gl2lds(Ab + (size_t)r1 * K + k0 + c1, lA1);
    gl2lds(Wb + (size_t)r0 * K + k0 + c0, lB0);
    gl2lds(Wb + (size_t)r1 * K + k0 + c1, lB1);
    __syncthreads();
    s16x8 af[4], bf[4];
#pragma unroll
    for (int mi = 0; mi < 4; mi++)
      af[mi] = *(const s16x8*)(As + (wm + mi * 16 + l15) * 32 + quad * 8);
#pragma unroll
    for (int ni = 0; ni < 4; ni++)
      bf[ni] = *(const s16x8*)(Bs + (wn + ni * 16 + l15) * 32 + quad * 8);
#pragma unroll
    for (int mi = 0; mi < 4; mi++)
#pragma unroll
      for (int ni = 0; ni < 4; ni++)
        acc[mi][ni] = SWAP
            ? __builtin_amdgcn_mfma_f32_16x16x32_bf16(bf[ni], af[mi],
                                                      acc[mi][ni], 0, 0, 0)
            : __builtin_amdgcn_mfma_f32_16x16x32_bf16(af[mi], bf[ni],
                                                      acc[mi][ni], 0, 0, 0);
  }
}

// ---------------------------------------------------------------- QKV proj
// XCD-swizzled grid (768%8==0). z<2: SWAPPED core -> fragment has s in l15,
// d in quad*4+r: RoPE pair (d,d^1) = (r even, r odd) thread-local; 4 d's
// pack into one u64 store. z=2 (V): unswapped, packed-u64 over s (as before).
template <bool TAB>
__global__ __launch_bounds__(256) void gemm_qkv_t(
    const u16* __restrict__ xb,
    const u16* __restrict__ wq, const u16* __restrict__ wk,
    const u16* __restrict__ wv, const int* __restrict__ pos,
    const float* __restrict__ rtab,
    u16* __restrict__ qh, u16* __restrict__ kh, u16* __restrict__ vt) {
  __shared__ __align__(16) u16 As[128 * 32];
  __shared__ __align__(16) u16 Bs[128 * 32];
  __shared__ __align__(16) float tabl[TAB ? 2 : 128 * 32 * 2];
  int id = blockIdx.x + 8 * blockIdx.y + 256 * blockIdx.z;
  int nid = (id & 7) * 96 + (id >> 3);          // XCD swizzle
  int bx = nid & 7, by = (nid >> 3) & 31, z = nid >> 8;
  const u16* W = (z == 0) ? wq : (z == 1) ? wk : wv;
  int bm0 = by * 128, bn0 = bx * 128;
  int tid = threadIdx.x;
  if (!TAB && z < 2) {
    for (int idx = tid; idx < 4096; idx += 256) {
      int rl = idx >> 5, pair = idx & 31;
      int s = (bm0 + rl) & 2047;
      float p = (float)pos[s];
      float freq = __expf(-0.28782313662425572f * (float)pair);
      float sn, cs;
      sincosf(p * freq, &sn, &cs);
      tabl[idx * 2] = cs;
      tabl[idx * 2 + 1] = sn;
    }
  }
  f32x4 acc[4][4];
  const f32x4 fz = {0.f, 0.f, 0.f, 0.f};
#pragma unroll
  for (int mi = 0; mi < 4; mi++)
#pragma unroll
    for (int ni = 0; ni < 4; ni++) acc[mi][ni] = fz;
  int wid = tid >> 6, lane = tid & 63;
  int quad = lane >> 4, l15 = lane & 15;
  int wm = (wid >> 1) * 64, wn = (wid & 1) * 64;
  if (z < 2) {
    gemm_core<true>(xb, W, As, Bs, bm0, bn0, acc);
    u16* dst = (z == 0) ? qh : kh;
    float qs = (z == 0) ? 0.125f : 1.0f;
    int h2 = (bn0 + wn) >> 6;               // (bn0+wn) is 64-aligned
#pragma unroll
    for (int mi = 0; mi < 4; mi++) {
      int rowg = bm0 + wm + mi * 16 + l15;  // s in lane dim
      int b2 = rowg >> 11, s2 = rowg & 2047;
      int rl = wm + mi * 16 + l15;          // local row for tabl
#pragma unroll
      for (int ni = 0; ni < 4; ni++) {
        int d0 = ni * 16 + quad * 4;        // 4 consecutive d in regs
        float cs0, sn0, cs1, sn1;
        if (TAB) {
          float2 t0 = *(const float2*)(rtab + (size_t)(s2 * 32 + (d0 >> 1)) * 2);
          float2 t1 = *(const float2*)(rtab + (size_t)(s2 * 32 + (d0 >> 1) + 1) * 2);
          cs0 = t0.x; sn0 = t0.y; cs1 = t1.x; sn1 = t1.y;
        } else {
          cs0 = tabl[(rl * 32 + (d0 >> 1)) * 2];
          sn0 = tabl[(rl * 32 + (d0 >> 1)) * 2 + 1];
          cs1 = tabl[(rl * 32 + (d0 >> 1) + 1) * 2];
          sn1 = tabl[(rl * 32 + (d0 >> 1) + 1) * 2 + 1];
        }
        float v0 = acc[mi][ni][0], v1 = acc[mi][ni][1];
        float v2 = acc[mi][ni][2], v3 = acc[mi][ni][3];
        float o0 = (v0 * cs0 - v1 * sn0) * qs;
        float o1 = (v0 * sn0 + v1 * cs0) * qs;
        float o2 = (v2 * cs1 - v3 * sn1) * qs;
        float o3 = (v2 * sn1 + v3 * cs1) * qs;
        u64 pk = (u64)f2bf(o0) | ((u64)f2bf(o1) << 16) |
                 ((u64)f2bf(o2) << 32) | ((u64)f2bf(o3) << 48);
        *(u64*)(dst + (((size_t)(b2 * 16 + h2)) * 2048 + s2) * 64 + d0) = pk;
      }
    }
  } else {
    gemm_core<false>(xb, W, As, Bs, bm0, bn0, acc);
#pragma unroll
    for (int mi = 0; mi < 4; mi++)
#pragma unroll
      for (int ni = 0; ni < 4; ni++) {
        int row0 = bm0 + wm + mi * 16 + quad * 4;
        int col = bn0 + wn + ni * 16 + l15;
        int b = row0 >> 11, s0 = row0 & 2047, h = col >> 6, d = col & 63;
        u64 pk = (u64)f2bf(acc[mi][ni][0]) |
                 ((u64)f2bf(acc[mi][ni][1]) << 16) |
                 ((u64)f2bf(acc[mi][ni][2]) << 32) |
                 ((u64)f2bf(acc[mi][ni][3]) << 48);
        *(u64*)(vt + (((size_t)(b * 16 + h)) * 64 + d) * 2048 + s0) = pk;
      }
  }
}

// ---------------------------------------------------------------- out proj
// N=64 tiles: C[128x64] = A[128x1024].Wo[64x1024]^T. Grid (16,32) = 512
// blocks = 2/CU (no split-K partials, no add kernel). Per wave: 32x64
// output, acc[2][4], 8 MFMA + 3 gl2lds per K-step. XCD-swizzled.
__global__ __launch_bounds__(256) void gemm_out_n64(
    const u16* __restrict__ ao, const u16* __restrict__ wo,
    float* __restrict__ out) {
  __shared__ __align__(16) u16 As[128 * 32];   // 8KB
  __shared__ __align__(16) u16 Bs[64 * 32];    // 4KB
  const int K = 1024;
  int id = blockIdx.x + 16 * blockIdx.y;
  int nid = (id & 7) * 64 + (id >> 3);         // XCD swizzle (512%8==0)
  int bx = nid & 15, by = nid >> 4;
  int bm0 = by * 128, bn0 = bx * 64;
  int tid = threadIdx.x;
  int wid = tid >> 6, lane = tid & 63, quad = lane >> 4, l15 = lane & 15;
  int wm = wid * 32;
  // A staging: 512 chunks, 2 wave-loads/wave; B: 256 chunks, 1/wave.
  int ch0 = wid * 128 + lane, ch1 = ch0 + 64;
  int ra0 = ch0 >> 2, ca0 = (ch0 & 3) * 8;
  int ra1 = ch1 >> 2, ca1 = (ch1 & 3) * 8;
  int chB = wid * 64 + lane;
  int rb = chB >> 2, cb = (chB & 3) * 8;
  const u16* Ab = ao + (size_t)bm0 * K;
  const u16* Wb = wo + (size_t)bn0 * K;
  u16* lA0 = As + wid * 1024; u16* lA1 = lA0 + 512;
  u16* lB0 = Bs + wid * 512;
  f32x4 acc[2][4];
  const f32x4 fz = {0.f, 0.f, 0.f, 0.f};
#pragma unroll
  for (int mi = 0; mi < 2; mi++)
#pragma unroll
    for (int ni = 0; ni < 4; ni++) acc[mi][ni] = fz;
  for (int k0 = 0; k0 < K; k0 += 32) {
    __syncthreads();
    gl2lds(Ab + (size_t)ra0 * K + k0 + ca0, lA0);
    gl2lds(Ab + (size_t)ra1 * K + k0 + ca1, lA1);
    gl2lds(Wb + (size_t)rb * K + k0 + cb, lB0);
    __syncthreads();
    s16x8 af[2], bf[4];
#pragma unroll
    for (int mi = 0; mi < 2; mi++)
      af[mi] = *(const s16x8*)(As + (wm + mi * 16 + l15) * 32 + quad * 8);
#pragma unroll
    for (int ni = 0; ni < 4; ni++)
      bf[ni] = *(const s16x8*)(Bs + (ni * 16 + l15) * 32 + quad * 8);
#pragma unroll
    for (int mi = 0; mi < 2; mi++)
#pragma unroll
      for (int ni = 0; ni < 4; ni++)
        acc[mi][ni] = __builtin_amdgcn_mfma_f32_16x16x32_bf16(
            af[mi], bf[ni], acc[mi][ni], 0, 0, 0);
  }
#pragma unroll
  for (int mi = 0; mi < 2; mi++)
#pragma unroll
    for (int ni = 0; ni < 4; ni++)
#pragma unroll
      for (int r = 0; r < 4; r++) {
        int row = bm0 + wm + mi * 16 + quad * 4 + r;
        int col = bn0 + ni * 16 + l15;
        out[(size_t)row * 1024 + col] = acc[mi][ni][r];
      }
}

// ---------------------------------------------------------------- attention
// R7-proven: R0 per-wave pipeline, QBLK=64 via 8 waves (512 thr).
#define KTS 72
#define VTS 72
#define PTS 40
#define OTS 72

__global__ __launch_bounds__(512, 4) void attn_k(
    const u16* __restrict__ qh, const u16* __restrict__ kh,
    const u16* __restrict__ vt, u16* __restrict__ ao) {
  __shared__ __align__(16) u16 kv[64 * KTS + 64 * VTS];  // K tile then V tile
  __shared__ __align__(16) u16 pt[8 * 16 * PTS];         // per-wave P^T + ow
  __shared__ __align__(16) float redl2[256];             // lsum partials
  u16* ks = kv;
  u16* vs = kv + 64 * KTS;
  int bid = blockIdx.x;
  int bh = bid & 31, pi = bid >> 5;        // pi 0..15
  int b = bh >> 4, h = bh & 15;
  int tid = threadIdx.x, wid = tid >> 6, lane = tid & 63;
  int quad = lane >> 4, l15 = lane & 15;
  int qsub = wid & 3, thalf = wid >> 2;
  const u16* qbase = qh + (size_t)bh * 2048 * 64;
  const u16* kbase = kh + (size_t)bh * 2048 * 64;
  const u16* vbase = vt + (size_t)bh * 64 * 2048;
  u16* ptw = pt + wid * 16 * PTS;
  const f32x4 fz = {0.f, 0.f, 0.f, 0.f};
  int srow = tid >> 3, sc = (tid & 7) * 8;  // 512 thr: 1 uint4/thread/array
  int tb = thalf * 32;

#pragma unroll
  for (int phase = 0; phase < 2; phase++) {
    int qt = phase ? (31 - pi) : pi;       // q-tile of 64
    int q0 = qt * 64, q0w = q0 + qsub * 16;
    s16x8 qf0 = *(const s16x8*)(qbase + (size_t)(q0w + l15) * 64 + quad * 8);
    s16x8 qf1 = *(const s16x8*)(qbase + (size_t)(q0w + l15) * 64 + 32 + quad * 8);
    f32x4 acc[4];
#pragma unroll
    for (int md = 0; md < 4; md++) acc[md] = fz;
    float lsum = 0.f;
    int qg = q0w + l15;
    int nt = qt + 1;
    uint4 rk0 = *(const uint4*)(kbase + (size_t)srow * 64 + sc);
    uint4 rv0 = *(const uint4*)(vbase + (size_t)srow * 2048 + sc);
    for (int it = 0; it < nt; it++) {
      __syncthreads();
      *(uint4*)(ks + srow * KTS + sc) = rk0;
      *(uint4*)(vs + srow * VTS + sc) = rv0;
      if (it + 1 < nt) {
        int t1 = (it + 1) << 6;
        rk0 = *(const uint4*)(kbase + (size_t)(t1 + srow) * 64 + sc);
        rv0 = *(const uint4*)(vbase + (size_t)srow * 2048 + t1 + sc);
      }
      __syncthreads();
      int t0 = it << 6;
      bool diag = (it == nt - 1);
#pragma unroll
      for (int mt = 0; mt < 2; mt++) {
        int krow = tb + mt * 16 + l15;
        s16x8 ka0 = *(const s16x8*)(ks + krow * KTS + quad * 8);
        s16x8 ka1 = *(const s16x8*)(ks + krow * KTS + 32 + quad * 8);
        f32x4 st = __builtin_amdgcn_mfma_f32_16x16x32_bf16(ka0, qf0, fz, 0, 0, 0);
        st = __builtin_amdgcn_mfma_f32_16x16x32_bf16(ka1, qf1, st, 0, 0, 0);
        u64 pk = 0;
#pragma unroll
        for (int r = 0; r < 4; r++) {
          float p = __expf(st[r]);
          if (diag) {
            int tg = t0 + tb + mt * 16 + quad * 4 + r;
            if (tg > qg) p = 0.f;
          }
          lsum += p;
          pk |= ((u64)f2bf(p)) << (16 * r);
        }
        *(u64*)(ptw + l15 * PTS + mt * 16 + quad * 4) = pk;
      }
      s16x8 pb = *(const s16x8*)(ptw + l15 * PTS + quad * 8);
#pragma unroll
      for (int md = 0; md < 4; md++) {
        s16x8 va = *(const s16x8*)(vs + (md * 16 + l15) * VTS + tb + quad * 8);
        acc[md] = __builtin_amdgcn_mfma_f32_16x16x32_bf16(va, pb, acc[md], 0, 0, 0);
      }
    }
    lsum += __shfl_xor(lsum, 16, 64);
    lsum += __shfl_xor(lsum, 32, 64);
    __syncthreads();
    float* redo = (float*)kv;              // 256 lanes x 16 f32 = 16KB <= kv
    if (thalf == 1) {
#pragma unroll
      for (int md = 0; md < 4; md++)
#pragma unroll
        for (int r = 0; r < 4; r++)
          redo[(qsub * 64 + lane) * 16 + md * 4 + r] = acc[md][r];
      redl2[qsub * 64 + lane] = lsum;
    }
    __syncthreads();
    if (thalf == 0) {
#pragma unroll
      for (int md = 0; md < 4; md++)
#pragma unroll
        for (int r = 0; r < 4; r++)
          acc[md][r] += redo[(qsub * 64 + lane) * 16 + md * 4 + r];
      lsum += redl2[qsub * 64 + lane];
      float rl = 1.0f / lsum;
      u16* ow = pt + qsub * 16 * OTS;      // 4 x 2304B <= pt (10240B)
#pragma unroll
      for (int md = 0; md < 4; md++) {
        u64 ok = 0;
#pragma unroll
        for (int r = 0; r < 4; r++)
          ok |= ((u64)f2bf(acc[md][r] * rl)) << (16 * r);
        *(u64*)(ow + l15 * OTS + md * 16 + quad * 4) = ok;
      }
      int qq = lane >> 2, dc = lane & 3;
      uint4 o0 = *(uint4*)(ow + qq * OTS + dc * 16);
      uint4 o1 = *(uint4*)(ow + qq * OTS + dc * 16 + 8);
      size_t orow = (size_t)b * 2048 + q0 + qsub * 16 + qq;
      *(uint4*)(ao + orow * 1024 + h * 64 + dc * 16) = o0;
      *(uint4*)(ao + orow * 1024 + h * 64 + dc * 16 + 8) = o1;
    }
  }
}

// ---------------------------------------------------------------- launch
extern "C" void kernel_launch(void* const* d_in, const int* in_sizes, int n_in,
                              void* d_out, int out_size, void* d_ws,
                              size_t ws_size, hipStream_t stream) {
  const float* x  = (const float*)d_in[0];
  const int* pos  = (const int*)d_in[1];
  const float* Wq = (const float*)d_in[2];
  const float* Wk = (const float*)d_in[3];
  const float* Wv = (const float*)d_in[4];
  const float* Wo = (const float*)d_in[5];
  float* out = (float*)d_out;

  char* ws = (char*)d_ws;
  const size_t MB = 1u << 20;
  u16* xb  = (u16*)(ws);             // 8 MB  [4096][1024] bf16
  u16* wqb = (u16*)(ws + 8 * MB);
  u16* wkb = (u16*)(ws + 10 * MB);
  u16* wvb = (u16*)(ws + 12 * MB);
  u16* wob = (u16*)(ws + 14 * MB);
  u16* qhb = (u16*)(ws + 16 * MB);   // [B][NH][S][HD]  (RoPE'd, Q scaled)
  u16* khb = (u16*)(ws + 24 * MB);
  u16* vtb = (u16*)(ws + 32 * MB);   // [B][NH][HD][S]
  float* rtab = (float*)(ws + 40 * MB);  // 512 KB RoPE (cos,sin) table
  u16* ao  = xb;  // xb dead after gemm_qkv

  bool tabok = ws_size >= 41 * MB;   // rtab fits

  cvt_all<<<tabok ? 8448 : 8192, 256, 0, stream>>>(
      x, Wq, Wk, Wv, Wo, xb, wqb, wkb, wvb, wob, rtab, pos);
  if (tabok)
    gemm_qkv_t<true><<<dim3(8, 32, 3), 256, 0, stream>>>(
        xb, wqb, wkb, wvb, pos, rtab, qhb, khb, vtb);
  else
    gemm_qkv_t<false><<<dim3(8, 32, 3), 256, 0, stream>>>(
        xb, wqb, wkb, wvb, pos, rtab, qhb, khb, vtb);
  attn_k<<<512, 512, 0, stream>>>(qhb, khb, vtb, ao);
  gemm_out_n64<<<dim3(16, 32), 256, 0, stream>>>(ao, wob, out);
}